// Round 10
// baseline (498.484 us; speedup 1.0000x reference)
//
#include <hip/hip_runtime.h>

typedef _Float16 half_t;
typedef half_t half4 __attribute__((ext_vector_type(4)));
typedef half_t half8 __attribute__((ext_vector_type(8)));
typedef float  f32x4 __attribute__((ext_vector_type(4)));
typedef float  f32x2 __attribute__((ext_vector_type(2)));

constexpr int B_  = 8;
constexpr int S_  = 15;
constexpr int K_  = 17;
constexpr int P_  = 31;
constexpr int SS_ = 225;
constexpr int PP_ = 961;
constexpr int KK_ = 289;

constexpr int NROW_C = B_ * PP_;          // 7688
constexpr int NROW_T = B_ * SS_;          // 1800
constexpr int NROW   = NROW_C + NROW_T;   // 9488

constexpr int WTOT = 131072;              // w0T [512][256] only
constexpr int NF16 = 128*256 + 64*128 + 32*64;   // w1h | w2h | w3h

// workspace float offsets
constexpr size_t OFF_WF   = 0;
constexpr size_t OFF_IN   = WTOT;
constexpr size_t OFF_OUT0 = OFF_IN   + (size_t)NROW * 256;
constexpr size_t OFF_ROWS = OFF_OUT0 + (size_t)NROW * 512;
constexpr size_t OFF_M0   = OFF_ROWS + (size_t)B_ * 31 * 17 * 256;
constexpr size_t OFF_TM0  = OFF_M0   + (size_t)B_ * KK_ * 256;
constexpr size_t OFF_W1H  = OFF_TM0  + (size_t)B_ * 256;

// chain LDS byte offsets
constexpr int X0B  = 0;       // f16 x0 [64][512B] swz (x2 [64][128B] swz aliases)
constexpr int X1B  = 32768;   // f16 x1 [64][256B] swz
constexpr int X3TB = 32768;   // f32 x3T [64][36f] (alias x1, 9216 B)
constexpr int Y4B  = 41984;   // f32 y4T [64][20f] (5120 B)
constexpr int SMB  = 49152;   // 240 f logits
constexpr int REDB = 50112;   // 16 f
constexpr int W4B  = 50176;   // w4 [16][36f] (2304 B)
constexpr int W5B  = 52480;   // w5 [8][20f]  (640 B)
constexpr int W6B  = 53120;   // w6 [8] (32 B)
constexpr int LDSB = 53152;

// ---------------------------------------------------------------------------
__global__ __launch_bounds__(256) void prep_kernel(
    const float* __restrict__ templ, const float* __restrict__ cand,
    const float* __restrict__ w0, const float* __restrict__ w1,
    const float* __restrict__ w2, const float* __restrict__ w3,
    float* __restrict__ inarr, float* __restrict__ wf,
    half_t* __restrict__ w1h, half_t* __restrict__ w2h,
    half_t* __restrict__ w3h)
{
  const int NA = NROW_C * 256;
  const int NB = NROW_T * 256;
  const int total = NA + NB + WTOT + NF16;
  for (int idx = blockIdx.x * blockDim.x + threadIdx.x; idx < total;
       idx += gridDim.x * blockDim.x) {
    if (idx < NA) {
      int c = idx & 255; int r = idx >> 8;
      int q = r % P_; int p = (r / P_) % P_; int b = r / PP_;
      inarr[idx] = cand[((b * 256 + c) * P_ + p) * P_ + q];
    } else if (idx < NA + NB) {
      int t = idx - NA;
      int c = t & 255; int r = t >> 8;
      int j = r % S_; int i = (r / S_) % S_; int b = r / SS_;
      inarr[idx] = templ[((b * 256 + c) * S_ + i) * S_ + j];
    } else if (idx < NA + NB + WTOT) {
      int t = idx - NA - NB;
      int o = t & 255; int c = t >> 8;
      wf[t] = w0[o * 512 + c];
    } else {
      int t = idx - NA - NB - WTOT;
      if (t < 32768)      w1h[t] = (half_t)w1[t];                  // [128][256]
      else if (t < 40960) w2h[t - 32768] = (half_t)w2[t - 32768];  // [64][128]
      else                w3h[t - 40960] = (half_t)w3[t - 40960];  // [32][64]
    }
  }
}

// ---------------------------------------------------------------------------
__global__ __launch_bounds__(256) void l0gemm_kernel(
    const float* __restrict__ in, const float* __restrict__ w0T,
    float* __restrict__ out0)
{
  __shared__ float X[256 * 17];
  const int tid = threadIdx.x;
  const int row0 = blockIdx.x * 16;
#pragma unroll
  for (int r = 0; r < 16; ++r)
    X[tid * 17 + r] = in[(size_t)(row0 + r) * 256 + tid];
  __syncthreads();
  float accA[16], accB[16];
#pragma unroll
  for (int r = 0; r < 16; ++r) { accA[r] = 0.f; accB[r] = 0.f; }
  for (int c = 0; c < 256; ++c) {
    float wA = w0T[c * 256 + tid];
    float wB = w0T[(256 + c) * 256 + tid];
#pragma unroll
    for (int r = 0; r < 16; ++r) {
      float x = X[c * 17 + r];
      accB[r] = fmaf(wB, x, accB[r]);
      accA[r] = fmaf(wA, x, accA[r]);
    }
  }
#pragma unroll
  for (int r = 0; r < 16; ++r) {
    out0[(size_t)(row0 + r) * 512 + tid]       = accB[r];
    out0[(size_t)(row0 + r) * 512 + 256 + tid] = accA[r];
  }
}

// ---------------------------------------------------------------------------
__global__ __launch_bounds__(256) void rowsum_kernel(
    const float* __restrict__ out0, float* __restrict__ rows)
{
  const int bid = blockIdx.x;
  const int o = threadIdx.x;
  const int v = bid % 17; const int p = (bid / 17) % 31; const int b = bid / (17 * 31);
  float s = 0.f;
  for (int j = 0; j < 15; ++j)
    s += out0[(size_t)(b * PP_ + p * P_ + v + j) * 512 + 256 + o];
  rows[(size_t)bid * 256 + o] = s;
}

__global__ __launch_bounds__(256) void colsum_kernel(
    const float* __restrict__ rows, float* __restrict__ m0v)
{
  const int bid = blockIdx.x;
  const int o = threadIdx.x;
  const int v = bid % 17; const int u = (bid / 17) % 17; const int b = bid / KK_;
  float s = 0.f;
  for (int i = 0; i < 15; ++i)
    s += rows[(size_t)((b * 31 + u + i) * 17 + v) * 256 + o];
  m0v[(size_t)bid * 256 + o] = s * (1.0f / 225.0f);
}

__global__ __launch_bounds__(256) void tmean0_kernel(
    const float* __restrict__ out0, float* __restrict__ tm0v)
{
  const int b = blockIdx.x;
  const int o = threadIdx.x;
  float s = 0.f;
  for (int t = 0; t < SS_; ++t)
    s += out0[(size_t)(NROW_C + b * SS_ + t) * 512 + 256 + o];
  tm0v[b * 256 + o] = s * (1.0f / 225.0f);
}

// ---------------------------------------------------------------------------
__global__ __launch_bounds__(512, 4) void chain_kernel(
    const float* __restrict__ out0, const float* __restrict__ m0v,
    const float* __restrict__ tm0v,
    const half_t* __restrict__ w1h, const half_t* __restrict__ w2h,
    const half_t* __restrict__ w3h,
    const float* __restrict__ w4, const float* __restrict__ w5,
    const float* __restrict__ w6,
    const float* __restrict__ inarr, float* __restrict__ out)
{
  __shared__ __align__(16) char lds[LDSB];
  float* ldsf = (float*)lds;
  float* sm   = (float*)(lds + SMB);
  float* red  = (float*)(lds + REDB);

  const int tid  = threadIdx.x;
  const int lane = tid & 63;
  const int wvs  = __builtin_amdgcn_readfirstlane(tid >> 6);
  const int bid  = (blockIdx.x & 7) * 290 + (blockIdx.x >> 3);   // XCD swizzle (2320 = 8*290)
  const bool is_t = (bid >= B_ * KK_);
  int b, u = 0, v = 0;
  const float* mean_vec;
  if (!is_t) {
    b = bid / KK_;
    int r = bid % KK_;
    u = r / K_; v = r % K_;
    mean_vec = m0v + (size_t)bid * 256;
  } else {
    b = bid - B_ * KK_;
    mean_vec = tm0v + (size_t)b * 256;
  }

  // one-time LDS weight staging (ordered before first use by B1..B4)
  ((float*)(lds + W4B))[(tid >> 5) * 36 + (tid & 31)] = w4[tid];       // [16][36f]
  if (tid < 128) ((float*)(lds + W5B))[(tid >> 4) * 20 + (tid & 15)] = w5[tid]; // [8][20f]
  if (tid < 8)   ((float*)(lds + W6B))[tid] = w6[tid];

  // hoisted MFMA A-fragments
  half8 af1[8];
  {
    const half_t* base = w1h + (size_t)(16 * wvs + (lane & 15)) * 256 + ((lane >> 4) << 3);
#pragma unroll
    for (int kb = 0; kb < 8; ++kb) af1[kb] = *(const half8*)(base + kb * 32);
  }
  const int g2 = wvs & 3, h2 = wvs >> 2;
  half8 af2[4];
  {
    const half_t* base = w2h + (size_t)(16 * g2 + (lane & 15)) * 128 + ((lane >> 4) << 3);
#pragma unroll
    for (int kb = 0; kb < 4; ++kb) af2[kb] = *(const half8*)(base + kb * 32);
  }
  const int rt3 = wvs & 1, ct3 = wvs >> 1;
  const half_t* b3ptr = w3h + (size_t)(16 * rt3 + (lane & 15)) * 64 + ((lane >> 4) << 3);
  const f32x4 mv4 = *(const f32x4*)(mean_vec + 4 * lane);

  // staging helper: x0[t][256ch] = f16(leaky(mean + conv1_window)), swizzled
  auto stage = [&](int s0) {
    for (int t = wvs; t < 64; t += 8) {
      int s = min(s0 + t, SS_ - 1);
      size_t row;
      if (!is_t) { int i = s / 15, j = s - i * 15; row = (size_t)(b * PP_ + (u + i) * P_ + (v + j)); }
      else       { row = (size_t)(NROW_C + b * SS_ + s); }
      f32x4 x = *(const f32x4*)(out0 + row * 512 + 4 * lane);
      half4 h;
#pragma unroll
      for (int r = 0; r < 4; ++r) {
        float a = x[r] + mv4[r];
        a = fmaxf(a, 0.01f * a);
        h[r] = (half_t)a;
      }
      const int off = (t * 512 + lane * 8) ^ ((t & 7) << 4);
      *(half4*)(lds + X0B + off) = h;
    }
  };

  stage(0);
  __syncthreads();

  for (int ti = 0; ti < 4; ++ti) {
    const int s0 = ti * 64;
    const int cnt = min(64, SS_ - s0);

    // ---- layer 1: 256 -> 128 MFMA (wave owns 16 out-ch, all 64 pos)
    f32x4 acc[4];
#pragma unroll
    for (int nt = 0; nt < 4; ++nt) acc[nt] = (f32x4){0.f, 0.f, 0.f, 0.f};
#pragma unroll
    for (int kb = 0; kb < 8; ++kb) {
      const int kbyte = kb * 64 + ((lane >> 4) << 4);
#pragma unroll
      for (int nt = 0; nt < 4; ++nt) {
        const int pos = nt * 16 + (lane & 15);
        const int off = (pos * 512 + kbyte) ^ ((pos & 7) << 4);
        half8 bfr = *(const half8*)(lds + X0B + off);
        acc[nt] = __builtin_amdgcn_mfma_f32_16x16x32_f16(af1[kb], bfr, acc[nt], 0, 0, 0);
      }
    }
#pragma unroll
    for (int nt = 0; nt < 4; ++nt) {
      const int pos = nt * 16 + (lane & 15);
      half4 h;
#pragma unroll
      for (int r = 0; r < 4; ++r) {
        float a = acc[nt][r];
        a = fmaxf(a, 0.01f * a);
        h[r] = (half_t)a;
      }
      const int ch0 = 16 * wvs + ((lane >> 4) << 2);
      const int off = (pos * 256 + ch0 * 2) ^ ((pos & 7) << 4);
      *(half4*)(lds + X1B + off) = h;
    }
    __syncthreads();

    // ---- layer 2: 128 -> 64 MFMA; epilogue -> x2 f16 [pos][64ch] swz
    f32x4 acc2[2];
#pragma unroll
    for (int nt = 0; nt < 2; ++nt) acc2[nt] = (f32x4){0.f, 0.f, 0.f, 0.f};
#pragma unroll
    for (int kb = 0; kb < 4; ++kb) {
      const int kbyte = kb * 64 + ((lane >> 4) << 4);
#pragma unroll
      for (int nt = 0; nt < 2; ++nt) {
        const int pos = h2 * 32 + nt * 16 + (lane & 15);
        const int off = (pos * 256 + kbyte) ^ ((pos & 7) << 4);
        half8 bfr = *(const half8*)(lds + X1B + off);
        acc2[nt] = __builtin_amdgcn_mfma_f32_16x16x32_f16(af2[kb], bfr, acc2[nt], 0, 0, 0);
      }
    }
#pragma unroll
    for (int nt = 0; nt < 2; ++nt) {
      const int pos = h2 * 32 + nt * 16 + (lane & 15);
      const int ch0 = 16 * g2 + ((lane >> 4) << 2);
      half4 h;
#pragma unroll
      for (int r = 0; r < 4; ++r) {
        float a = acc2[nt][r];
        a = fmaxf(a, 0.01f * a);
        h[r] = (half_t)a;
      }
      const int off = (pos * 128 + ch0 * 2) ^ ((pos & 7) << 4);
      *(half4*)(lds + X0B + off) = h;
    }
    __syncthreads();

    // ---- layer 3: 64 -> 32 MFMA; epilogue -> x3T f32 [pos][36f]
    {
      f32x4 acc3 = (f32x4){0.f, 0.f, 0.f, 0.f};
      const int pos = ct3 * 16 + (lane & 15);
#pragma unroll
      for (int kb = 0; kb < 2; ++kb) {
        half8 a3 = *(const half8*)(b3ptr + kb * 32);
        const int kbyte = kb * 64 + ((lane >> 4) << 4);
        const int off = (pos * 128 + kbyte) ^ ((pos & 7) << 4);
        half8 bfr = *(const half8*)(lds + X0B + off);
        acc3 = __builtin_amdgcn_mfma_f32_16x16x32_f16(a3, bfr, acc3, 0, 0, 0);
      }
      const int ch0 = 16 * rt3 + ((lane >> 4) << 2);
      f32x4 o4;
#pragma unroll
      for (int r = 0; r < 4; ++r) {
        float a = acc3[r];
        o4[r] = fmaxf(a, 0.01f * a);
      }
      *(f32x4*)(lds + X3TB + pos * 144 + ch0 * 4) = o4;
    }
    __syncthreads();

    // ---- layers 4-6, pos-sliced per wave (pos 8*wvs..+7), barrier-free
    {
      const int p = lane >> 3, g = lane & 7;
      const int pos = 8 * wvs + p;
      float a4_0 = 0.f, a4_1 = 0.f;
#pragma unroll
      for (int c0 = 0; c0 < 32; c0 += 4) {
        f32x4 x  = *(const f32x4*)(lds + X3TB + pos * 144 + c0 * 4);
        f32x4 wA = *(const f32x4*)(lds + W4B + (2 * g) * 144 + c0 * 4);
        f32x4 wB = *(const f32x4*)(lds + W4B + (2 * g + 1) * 144 + c0 * 4);
#pragma unroll
        for (int r = 0; r < 4; ++r) {
          a4_0 = fmaf(wA[r], x[r], a4_0);
          a4_1 = fmaf(wB[r], x[r], a4_1);
        }
      }
      f32x2 y4v;
      y4v[0] = fmaxf(a4_0, 0.01f * a4_0);
      y4v[1] = fmaxf(a4_1, 0.01f * a4_1);
      *(f32x2*)(lds + Y4B + pos * 80 + g * 8) = y4v;
      float a5 = 0.f;
#pragma unroll
      for (int c0 = 0; c0 < 16; c0 += 4) {
        f32x4 x = *(const f32x4*)(lds + Y4B + pos * 80 + c0 * 4);
        f32x4 w = *(const f32x4*)(lds + W5B + g * 80 + c0 * 4);
#pragma unroll
        for (int r = 0; r < 4; ++r) a5 = fmaf(w[r], x[r], a5);
      }
      a5 = fmaxf(a5, 0.01f * a5);
      float t6 = ((float*)(lds + W6B))[g] * a5;
      t6 += __shfl_xor(t6, 1);
      t6 += __shfl_xor(t6, 2);
      t6 += __shfl_xor(t6, 4);
      if (g == 0 && (8 * wvs + p) < cnt) sm[s0 + pos] = t6;
    }

    // ---- prefetch next tile's x0 (disjoint LDS region; overlaps tail)
    if (ti < 3) stage(s0 + 64);
    __syncthreads();
  }

  // ---- softmax over 225 logits
  float vv = (tid < SS_) ? sm[tid] : -1e30f;
  float m = vv;
#pragma unroll
  for (int off = 32; off >= 1; off >>= 1) m = fmaxf(m, __shfl_xor(m, off));
  if (lane == 0) red[wvs] = m;
  __syncthreads();
  m = red[0];
#pragma unroll
  for (int w = 1; w < 8; ++w) m = fmaxf(m, red[w]);
  float e = (tid < SS_) ? __expf(vv - m) : 0.f;
  float ss = e;
#pragma unroll
  for (int off = 32; off >= 1; off >>= 1) ss += __shfl_xor(ss, off);
  __syncthreads();
  if (lane == 0) red[wvs] = ss;
  __syncthreads();
  float Stot = red[0];
#pragma unroll
  for (int w = 1; w < 8; ++w) Stot += red[w];
  if (tid < SS_) sm[tid] = e / Stot;
  __syncthreads();

  // ---- weighted channel sum over raw features
  const int c_st = tid & 255;
  const int h_st = tid >> 8;
  float acc3 = 0.f;
  if (!is_t) {
    for (int s = h_st; s < SS_; s += 2) {
      int i = s / 15, j = s - i * 15;
      size_t row = (size_t)b * PP_ + (u + i) * P_ + (v + j);
      acc3 = fmaf(sm[s], inarr[row * 256 + c_st], acc3);
    }
  } else {
    for (int s = h_st; s < SS_; s += 2)
      acc3 = fmaf(sm[s], inarr[(size_t)(NROW_C + b * SS_ + s) * 256 + c_st], acc3);
  }
  __syncthreads();
  ldsf[tid] = acc3;
  __syncthreads();
  if (tid < 256) {
    float tot = ldsf[tid] + ldsf[256 + tid];
    if (!is_t) out[2048 + ((size_t)(b * 256 + tid) * 17 + u) * 17 + v] = tot;
    else       out[b * 256 + tid] = tot;
  }
}

// ---------------------------------------------------------------------------
extern "C" void kernel_launch(void* const* d_in, const int* in_sizes, int n_in,
                              void* d_out, int out_size, void* d_ws, size_t ws_size,
                              hipStream_t stream)
{
  const float* templ = (const float*)d_in[0];
  const float* cand  = (const float*)d_in[1];
  const float* w0 = (const float*)d_in[2];
  const float* w1 = (const float*)d_in[3];
  const float* w2 = (const float*)d_in[4];
  const float* w3 = (const float*)d_in[5];
  const float* w4 = (const float*)d_in[6];
  const float* w5 = (const float*)d_in[7];
  const float* w6 = (const float*)d_in[8];

  float* ws    = (float*)d_ws;
  float* wf    = ws + OFF_WF;
  float* inarr = ws + OFF_IN;
  float* out0  = ws + OFF_OUT0;
  float* rows  = ws + OFF_ROWS;
  float* m0v   = ws + OFF_M0;
  float* tm0v  = ws + OFF_TM0;
  half_t* w1h  = (half_t*)(ws + OFF_W1H);
  half_t* w2h  = w1h + 128 * 256;
  half_t* w3h  = w2h + 64 * 128;
  float* outf  = (float*)d_out;

  prep_kernel<<<2048, 256, 0, stream>>>(templ, cand, w0, w1, w2, w3,
                                        inarr, wf, w1h, w2h, w3h);
  l0gemm_kernel<<<NROW / 16, 256, 0, stream>>>(inarr, wf, out0);
  rowsum_kernel<<<B_ * 31 * 17, 256, 0, stream>>>(out0, rows);
  colsum_kernel<<<B_ * KK_, 256, 0, stream>>>(rows, m0v);
  tmean0_kernel<<<B_, 256, 0, stream>>>(out0, tm0v);
  chain_kernel<<<B_ * KK_ + B_, 512, 0, stream>>>(out0, m0v, tm0v,
                                                  w1h, w2h, w3h, w4, w5, w6,
                                                  inarr, outf);
}

// Round 11
// 362.524 us; speedup vs baseline: 1.3750x; 1.3750x over previous
//
#include <hip/hip_runtime.h>

typedef _Float16 half_t;
typedef half_t half4 __attribute__((ext_vector_type(4)));
typedef half_t half8 __attribute__((ext_vector_type(8)));
typedef float  f32x4 __attribute__((ext_vector_type(4)));
typedef float  f32x2 __attribute__((ext_vector_type(2)));

constexpr int B_  = 8;
constexpr int S_  = 15;
constexpr int K_  = 17;
constexpr int P_  = 31;
constexpr int SS_ = 225;
constexpr int PP_ = 961;
constexpr int KK_ = 289;

constexpr int NROW_C = B_ * PP_;          // 7688
constexpr int NROW_T = B_ * SS_;          // 1800
constexpr int NROW   = NROW_C + NROW_T;   // 9488

constexpr int WTOT = 131072;              // w0T [512][256] only
constexpr int NF16 = 128*256 + 64*128 + 32*64;   // w1h | w2h | w3h

// workspace float offsets
constexpr size_t OFF_WF   = 0;
constexpr size_t OFF_IN   = WTOT;
constexpr size_t OFF_OUT0 = OFF_IN   + (size_t)NROW * 256;
constexpr size_t OFF_ROWS = OFF_OUT0 + (size_t)NROW * 512;
constexpr size_t OFF_M0   = OFF_ROWS + (size_t)B_ * 31 * 17 * 256;
constexpr size_t OFF_TM0  = OFF_M0   + (size_t)B_ * KK_ * 256;
constexpr size_t OFF_W1H  = OFF_TM0  + (size_t)B_ * 256;

// chain LDS byte offsets
constexpr int X0B  = 0;       // f16 x0 [64][512B] swz (x2 [64][128B] swz aliases)
constexpr int X1B  = 32768;   // f16 x1 [64][256B] swz
constexpr int X3TB = 32768;   // f32 x3T [64][36f] (alias x1, 9216 B)
constexpr int Y4B  = 41984;   // f32 y4T [64][20f] (5120 B)
constexpr int SMB  = 49152;   // 240 f logits
constexpr int REDB = 50112;   // 16 f
constexpr int W4B  = 50176;   // w4 [16][36f] (2304 B)
constexpr int W5B  = 52480;   // w5 [8][20f]  (640 B)
constexpr int W6B  = 53120;   // w6 [8] (32 B)
constexpr int LDSB = 53152;

// ---------------------------------------------------------------------------
__global__ __launch_bounds__(256) void prep_kernel(
    const float* __restrict__ templ, const float* __restrict__ cand,
    const float* __restrict__ w0, const float* __restrict__ w1,
    const float* __restrict__ w2, const float* __restrict__ w3,
    float* __restrict__ inarr, float* __restrict__ wf,
    half_t* __restrict__ w1h, half_t* __restrict__ w2h,
    half_t* __restrict__ w3h)
{
  const int NA = NROW_C * 256;
  const int NB = NROW_T * 256;
  const int total = NA + NB + WTOT + NF16;
  for (int idx = blockIdx.x * blockDim.x + threadIdx.x; idx < total;
       idx += gridDim.x * blockDim.x) {
    if (idx < NA) {
      int c = idx & 255; int r = idx >> 8;
      int q = r % P_; int p = (r / P_) % P_; int b = r / PP_;
      inarr[idx] = cand[((b * 256 + c) * P_ + p) * P_ + q];
    } else if (idx < NA + NB) {
      int t = idx - NA;
      int c = t & 255; int r = t >> 8;
      int j = r % S_; int i = (r / S_) % S_; int b = r / SS_;
      inarr[idx] = templ[((b * 256 + c) * S_ + i) * S_ + j];
    } else if (idx < NA + NB + WTOT) {
      int t = idx - NA - NB;
      int o = t & 255; int c = t >> 8;
      wf[t] = w0[o * 512 + c];
    } else {
      int t = idx - NA - NB - WTOT;
      if (t < 32768)      w1h[t] = (half_t)w1[t];                  // [128][256]
      else if (t < 40960) w2h[t - 32768] = (half_t)w2[t - 32768];  // [64][128]
      else                w3h[t - 40960] = (half_t)w3[t - 40960];  // [32][64]
    }
  }
}

// ---------------------------------------------------------------------------
__global__ __launch_bounds__(256) void l0gemm_kernel(
    const float* __restrict__ in, const float* __restrict__ w0T,
    float* __restrict__ out0)
{
  __shared__ float X[256 * 17];
  const int tid = threadIdx.x;
  const int row0 = blockIdx.x * 16;
#pragma unroll
  for (int r = 0; r < 16; ++r)
    X[tid * 17 + r] = in[(size_t)(row0 + r) * 256 + tid];
  __syncthreads();
  float accA[16], accB[16];
#pragma unroll
  for (int r = 0; r < 16; ++r) { accA[r] = 0.f; accB[r] = 0.f; }
  for (int c = 0; c < 256; ++c) {
    float wA = w0T[c * 256 + tid];
    float wB = w0T[(256 + c) * 256 + tid];
#pragma unroll
    for (int r = 0; r < 16; ++r) {
      float x = X[c * 17 + r];
      accB[r] = fmaf(wB, x, accB[r]);
      accA[r] = fmaf(wA, x, accA[r]);
    }
  }
#pragma unroll
  for (int r = 0; r < 16; ++r) {
    out0[(size_t)(row0 + r) * 512 + tid]       = accB[r];
    out0[(size_t)(row0 + r) * 512 + 256 + tid] = accA[r];
  }
}

// ---------------------------------------------------------------------------
__global__ __launch_bounds__(256) void rowsum_kernel(
    const float* __restrict__ out0, float* __restrict__ rows)
{
  const int bid = blockIdx.x;
  const int o = threadIdx.x;
  const int v = bid % 17; const int p = (bid / 17) % 31; const int b = bid / (17 * 31);
  float s = 0.f;
  for (int j = 0; j < 15; ++j)
    s += out0[(size_t)(b * PP_ + p * P_ + v + j) * 512 + 256 + o];
  rows[(size_t)bid * 256 + o] = s;
}

__global__ __launch_bounds__(256) void colsum_kernel(
    const float* __restrict__ rows, float* __restrict__ m0v)
{
  const int bid = blockIdx.x;
  const int o = threadIdx.x;
  const int v = bid % 17; const int u = (bid / 17) % 17; const int b = bid / KK_;
  float s = 0.f;
  for (int i = 0; i < 15; ++i)
    s += rows[(size_t)((b * 31 + u + i) * 17 + v) * 256 + o];
  m0v[(size_t)bid * 256 + o] = s * (1.0f / 225.0f);
}

__global__ __launch_bounds__(256) void tmean0_kernel(
    const float* __restrict__ out0, float* __restrict__ tm0v)
{
  const int b = blockIdx.x;
  const int o = threadIdx.x;
  float s = 0.f;
  for (int t = 0; t < SS_; ++t)
    s += out0[(size_t)(NROW_C + b * SS_ + t) * 512 + 256 + o];
  tm0v[b * 256 + o] = s * (1.0f / 225.0f);
}

// ---------------------------------------------------------------------------
__global__ __launch_bounds__(512, 4) void chain_kernel(
    const float* __restrict__ out0, const float* __restrict__ m0v,
    const float* __restrict__ tm0v,
    const half_t* __restrict__ w1h, const half_t* __restrict__ w2h,
    const half_t* __restrict__ w3h,
    const float* __restrict__ w4, const float* __restrict__ w5,
    const float* __restrict__ w6,
    const float* __restrict__ inarr, float* __restrict__ out)
{
  __shared__ __align__(16) char lds[LDSB];
  float* ldsf = (float*)lds;
  float* sm   = (float*)(lds + SMB);
  float* red  = (float*)(lds + REDB);

  const int tid  = threadIdx.x;
  const int lane = tid & 63;
  const int wvs  = __builtin_amdgcn_readfirstlane(tid >> 6);
  const int bid  = (blockIdx.x & 7) * 290 + (blockIdx.x >> 3);   // XCD swizzle (2320 = 8*290)
  const bool is_t = (bid >= B_ * KK_);
  int b, u = 0, v = 0;
  const float* mean_vec;
  if (!is_t) {
    b = bid / KK_;
    int r = bid % KK_;
    u = r / K_; v = r % K_;
    mean_vec = m0v + (size_t)bid * 256;
  } else {
    b = bid - B_ * KK_;
    mean_vec = tm0v + (size_t)b * 256;
  }

  // one-time LDS weight staging (ordered before first use)
  ((float*)(lds + W4B))[(tid >> 5) * 36 + (tid & 31)] = w4[tid];       // [16][36f]
  if (tid < 128) ((float*)(lds + W5B))[(tid >> 4) * 20 + (tid & 15)] = w5[tid]; // [8][20f]
  if (tid < 8)   ((float*)(lds + W6B))[tid] = w6[tid];

  // W1 fragment base (loads streamed per-tile inside L1 — NOT hoisted)
  const half_t* w1base = w1h + (size_t)(16 * wvs + (lane & 15)) * 256 + ((lane >> 4) << 3);
  // hoisted W2 fragments (16 VGPRs persistent)
  const int g2 = wvs & 3, h2 = wvs >> 2;
  half8 af2[4];
  {
    const half_t* base = w2h + (size_t)(16 * g2 + (lane & 15)) * 128 + ((lane >> 4) << 3);
#pragma unroll
    for (int kb = 0; kb < 4; ++kb) af2[kb] = *(const half8*)(base + kb * 32);
  }
  const int rt3 = wvs & 1, ct3 = wvs >> 1;
  const half_t* b3ptr = w3h + (size_t)(16 * rt3 + (lane & 15)) * 64 + ((lane >> 4) << 3);
  const f32x4 mv4 = *(const f32x4*)(mean_vec + 4 * lane);

  for (int ti = 0; ti < 4; ++ti) {
    const int s0 = ti * 64;
    const int cnt = min(64, SS_ - s0);

    // ---- stage x0 = f16(leaky(mean + conv1_window)), [pos][256ch] swz
    for (int t = wvs; t < 64; t += 8) {
      int s = min(s0 + t, SS_ - 1);
      size_t row;
      if (!is_t) { int i = s / 15, j = s - i * 15; row = (size_t)(b * PP_ + (u + i) * P_ + (v + j)); }
      else       { row = (size_t)(NROW_C + b * SS_ + s); }
      f32x4 x = *(const f32x4*)(out0 + row * 512 + 4 * lane);
      half4 h;
#pragma unroll
      for (int r = 0; r < 4; ++r) {
        float a = x[r] + mv4[r];
        a = fmaxf(a, 0.01f * a);
        h[r] = (half_t)a;
      }
      const int off = (t * 512 + lane * 8) ^ ((t & 7) << 4);
      *(half4*)(lds + X0B + off) = h;
    }
    __syncthreads();

    // ---- layer 1: 256 -> 128 MFMA; W1 fragments streamed (opaque ptr stops LICM)
    {
      const half_t* w1p = w1base;
      asm volatile("" : "+v"(w1p));   // defeat hoisting out of the ti loop
      f32x4 acc[4];
#pragma unroll
      for (int nt = 0; nt < 4; ++nt) acc[nt] = (f32x4){0.f, 0.f, 0.f, 0.f};
#pragma unroll 2
      for (int kb = 0; kb < 8; ++kb) {
        half8 a1 = *(const half8*)(w1p + kb * 32);
        const int kbyte = kb * 64 + ((lane >> 4) << 4);
#pragma unroll
        for (int nt = 0; nt < 4; ++nt) {
          const int pos = nt * 16 + (lane & 15);
          const int off = (pos * 512 + kbyte) ^ ((pos & 7) << 4);
          half8 bfr = *(const half8*)(lds + X0B + off);
          acc[nt] = __builtin_amdgcn_mfma_f32_16x16x32_f16(a1, bfr, acc[nt], 0, 0, 0);
        }
      }
#pragma unroll
      for (int nt = 0; nt < 4; ++nt) {
        const int pos = nt * 16 + (lane & 15);
        half4 h;
#pragma unroll
        for (int r = 0; r < 4; ++r) {
          float a = acc[nt][r];
          a = fmaxf(a, 0.01f * a);
          h[r] = (half_t)a;
        }
        const int ch0 = 16 * wvs + ((lane >> 4) << 2);
        const int off = (pos * 256 + ch0 * 2) ^ ((pos & 7) << 4);
        *(half4*)(lds + X1B + off) = h;
      }
    }
    __syncthreads();

    // ---- layer 2: 128 -> 64 MFMA; epilogue -> x2 f16 [pos][64ch] swz
    f32x4 acc2[2];
#pragma unroll
    for (int nt = 0; nt < 2; ++nt) acc2[nt] = (f32x4){0.f, 0.f, 0.f, 0.f};
#pragma unroll
    for (int kb = 0; kb < 4; ++kb) {
      const int kbyte = kb * 64 + ((lane >> 4) << 4);
#pragma unroll
      for (int nt = 0; nt < 2; ++nt) {
        const int pos = h2 * 32 + nt * 16 + (lane & 15);
        const int off = (pos * 256 + kbyte) ^ ((pos & 7) << 4);
        half8 bfr = *(const half8*)(lds + X1B + off);
        acc2[nt] = __builtin_amdgcn_mfma_f32_16x16x32_f16(af2[kb], bfr, acc2[nt], 0, 0, 0);
      }
    }
#pragma unroll
    for (int nt = 0; nt < 2; ++nt) {
      const int pos = h2 * 32 + nt * 16 + (lane & 15);
      const int ch0 = 16 * g2 + ((lane >> 4) << 2);
      half4 h;
#pragma unroll
      for (int r = 0; r < 4; ++r) {
        float a = acc2[nt][r];
        a = fmaxf(a, 0.01f * a);
        h[r] = (half_t)a;
      }
      const int off = (pos * 128 + ch0 * 2) ^ ((pos & 7) << 4);
      *(half4*)(lds + X0B + off) = h;
    }
    __syncthreads();

    // ---- layer 3: 64 -> 32 MFMA; epilogue -> x3T f32 [pos][36f]
    {
      f32x4 acc3 = (f32x4){0.f, 0.f, 0.f, 0.f};
      const int pos = ct3 * 16 + (lane & 15);
#pragma unroll
      for (int kb = 0; kb < 2; ++kb) {
        half8 a3 = *(const half8*)(b3ptr + kb * 32);
        const int kbyte = kb * 64 + ((lane >> 4) << 4);
        const int off = (pos * 128 + kbyte) ^ ((pos & 7) << 4);
        half8 bfr = *(const half8*)(lds + X0B + off);
        acc3 = __builtin_amdgcn_mfma_f32_16x16x32_f16(a3, bfr, acc3, 0, 0, 0);
      }
      const int ch0 = 16 * rt3 + ((lane >> 4) << 2);
      f32x4 o4;
#pragma unroll
      for (int r = 0; r < 4; ++r) {
        float a = acc3[r];
        o4[r] = fmaxf(a, 0.01f * a);
      }
      *(f32x4*)(lds + X3TB + pos * 144 + ch0 * 4) = o4;
    }
    __syncthreads();

    // ---- layers 4-6, pos-sliced per wave (pos 8*wvs..+7), barrier-free
    {
      const int p = lane >> 3, g = lane & 7;
      const int pos = 8 * wvs + p;
      float a4_0 = 0.f, a4_1 = 0.f;
#pragma unroll
      for (int c0 = 0; c0 < 32; c0 += 4) {
        f32x4 x  = *(const f32x4*)(lds + X3TB + pos * 144 + c0 * 4);
        f32x4 wA = *(const f32x4*)(lds + W4B + (2 * g) * 144 + c0 * 4);
        f32x4 wB = *(const f32x4*)(lds + W4B + (2 * g + 1) * 144 + c0 * 4);
#pragma unroll
        for (int r = 0; r < 4; ++r) {
          a4_0 = fmaf(wA[r], x[r], a4_0);
          a4_1 = fmaf(wB[r], x[r], a4_1);
        }
      }
      f32x2 y4v;
      y4v[0] = fmaxf(a4_0, 0.01f * a4_0);
      y4v[1] = fmaxf(a4_1, 0.01f * a4_1);
      *(f32x2*)(lds + Y4B + pos * 80 + g * 8) = y4v;
      float a5 = 0.f;
#pragma unroll
      for (int c0 = 0; c0 < 16; c0 += 4) {
        f32x4 x = *(const f32x4*)(lds + Y4B + pos * 80 + c0 * 4);
        f32x4 w = *(const f32x4*)(lds + W5B + g * 80 + c0 * 4);
#pragma unroll
        for (int r = 0; r < 4; ++r) a5 = fmaf(w[r], x[r], a5);
      }
      a5 = fmaxf(a5, 0.01f * a5);
      float t6 = ((float*)(lds + W6B))[g] * a5;
      t6 += __shfl_xor(t6, 1);
      t6 += __shfl_xor(t6, 2);
      t6 += __shfl_xor(t6, 4);
      if (g == 0 && (8 * wvs + p) < cnt) sm[s0 + pos] = t6;
    }
    __syncthreads();
  }

  // ---- softmax over 225 logits
  float vv = (tid < SS_) ? sm[tid] : -1e30f;
  float m = vv;
#pragma unroll
  for (int off = 32; off >= 1; off >>= 1) m = fmaxf(m, __shfl_xor(m, off));
  if (lane == 0) red[wvs] = m;
  __syncthreads();
  m = red[0];
#pragma unroll
  for (int w = 1; w < 8; ++w) m = fmaxf(m, red[w]);
  float e = (tid < SS_) ? __expf(vv - m) : 0.f;
  float ss = e;
#pragma unroll
  for (int off = 32; off >= 1; off >>= 1) ss += __shfl_xor(ss, off);
  __syncthreads();
  if (lane == 0) red[wvs] = ss;
  __syncthreads();
  float Stot = red[0];
#pragma unroll
  for (int w = 1; w < 8; ++w) Stot += red[w];
  if (tid < SS_) sm[tid] = e / Stot;
  __syncthreads();

  // ---- weighted channel sum over raw features
  const int c_st = tid & 255;
  const int h_st = tid >> 8;
  float acc3 = 0.f;
  if (!is_t) {
    for (int s = h_st; s < SS_; s += 2) {
      int i = s / 15, j = s - i * 15;
      size_t row = (size_t)b * PP_ + (u + i) * P_ + (v + j);
      acc3 = fmaf(sm[s], inarr[row * 256 + c_st], acc3);
    }
  } else {
    for (int s = h_st; s < SS_; s += 2)
      acc3 = fmaf(sm[s], inarr[(size_t)(NROW_C + b * SS_ + s) * 256 + c_st], acc3);
  }
  __syncthreads();
  ldsf[tid] = acc3;
  __syncthreads();
  if (tid < 256) {
    float tot = ldsf[tid] + ldsf[256 + tid];
    if (!is_t) out[2048 + ((size_t)(b * 256 + tid) * 17 + u) * 17 + v] = tot;
    else       out[b * 256 + tid] = tot;
  }
}

// ---------------------------------------------------------------------------
extern "C" void kernel_launch(void* const* d_in, const int* in_sizes, int n_in,
                              void* d_out, int out_size, void* d_ws, size_t ws_size,
                              hipStream_t stream)
{
  const float* templ = (const float*)d_in[0];
  const float* cand  = (const float*)d_in[1];
  const float* w0 = (const float*)d_in[2];
  const float* w1 = (const float*)d_in[3];
  const float* w2 = (const float*)d_in[4];
  const float* w3 = (const float*)d_in[5];
  const float* w4 = (const float*)d_in[6];
  const float* w5 = (const float*)d_in[7];
  const float* w6 = (const float*)d_in[8];

  float* ws    = (float*)d_ws;
  float* wf    = ws + OFF_WF;
  float* inarr = ws + OFF_IN;
  float* out0  = ws + OFF_OUT0;
  float* rows  = ws + OFF_ROWS;
  float* m0v   = ws + OFF_M0;
  float* tm0v  = ws + OFF_TM0;
  half_t* w1h  = (half_t*)(ws + OFF_W1H);
  half_t* w2h  = w1h + 128 * 256;
  half_t* w3h  = w2h + 64 * 128;
  float* outf  = (float*)d_out;

  prep_kernel<<<2048, 256, 0, stream>>>(templ, cand, w0, w1, w2, w3,
                                        inarr, wf, w1h, w2h, w3h);
  l0gemm_kernel<<<NROW / 16, 256, 0, stream>>>(inarr, wf, out0);
  rowsum_kernel<<<B_ * 31 * 17, 256, 0, stream>>>(out0, rows);
  colsum_kernel<<<B_ * KK_, 256, 0, stream>>>(rows, m0v);
  tmean0_kernel<<<B_, 256, 0, stream>>>(out0, tm0v);
  chain_kernel<<<B_ * KK_ + B_, 512, 0, stream>>>(out0, m0v, tm0v,
                                                  w1h, w2h, w3h, w4, w5, w6,
                                                  inarr, outf);
}

// Round 13
// 349.628 us; speedup vs baseline: 1.4258x; 1.0369x over previous
//
#include <hip/hip_runtime.h>

typedef _Float16 half_t;
typedef half_t half4 __attribute__((ext_vector_type(4)));
typedef half_t half8 __attribute__((ext_vector_type(8)));
typedef float  f32x4 __attribute__((ext_vector_type(4)));
typedef float  f32x2 __attribute__((ext_vector_type(2)));

constexpr int B_  = 8;
constexpr int S_  = 15;
constexpr int K_  = 17;
constexpr int P_  = 31;
constexpr int SS_ = 225;
constexpr int PP_ = 961;
constexpr int KK_ = 289;

constexpr int NROW_C = B_ * PP_;          // 7688
constexpr int NROW_T = B_ * SS_;          // 1800
constexpr int NROW   = NROW_C + NROW_T;   // 9488 = 593*16

constexpr int NW0H = 512 * 256;                   // w0h f16 (conv1 rows | g rows)
constexpr int NF16 = 128*256 + 64*128 + 32*64;    // w1h | w2h | w3h

// workspace float offsets
constexpr size_t OFF_IN   = 0;
constexpr size_t OFF_OUT0 = OFF_IN   + (size_t)NROW * 256;
constexpr size_t OFF_ROWS = OFF_OUT0 + (size_t)NROW * 512;
constexpr size_t OFF_M0   = OFF_ROWS + (size_t)B_ * 31 * 17 * 256;
constexpr size_t OFF_TM0  = OFF_M0   + (size_t)B_ * KK_ * 256;
constexpr size_t OFF_F16  = OFF_TM0  + (size_t)B_ * 256;   // f16 arena

// chain LDS byte offsets (36,768 B -> 4 blocks/CU)
// transient: X0B 0..16384 (x0 half-K [64][256B] swz; x2 [64][128B] aliases)
//            X1B 16384..32768 (x1 [64][256B] swz; x3T + y4T alias after L2)
constexpr int X0B  = 0;
constexpr int X1B  = 16384;
constexpr int X3TB = 16384;   // f32 x3T [64][36f] (alias dead x1, 9216 B)
constexpr int Y4B  = 25600;   // f32 y4T [64][20f] (alias dead x1, 5120 B)
// persistent (must NOT overlap x1's 16384..32768 span):
constexpr int SMB  = 32768;   // 240 f logits
constexpr int REDB = 33728;   // 16 f
constexpr int W4B  = 33792;   // w4 [16][36f] (2304 B)
constexpr int W5B  = 36096;   // w5 [8][20f]  (640 B)
constexpr int W6B  = 36736;   // w6 [8] (32 B)
constexpr int LDSB = 36768;

// ---------------------------------------------------------------------------
__global__ __launch_bounds__(256) void prep_kernel(
    const float* __restrict__ templ, const float* __restrict__ cand,
    const float* __restrict__ w0, const float* __restrict__ w1,
    const float* __restrict__ w2, const float* __restrict__ w3,
    float* __restrict__ inarr, half_t* __restrict__ w0h,
    half_t* __restrict__ w1h, half_t* __restrict__ w2h,
    half_t* __restrict__ w3h)
{
  const int NA = NROW_C * 256;
  const int NB = NROW_T * 256;
  const int total = NA + NB + NW0H + NF16;
  for (int idx = blockIdx.x * blockDim.x + threadIdx.x; idx < total;
       idx += gridDim.x * blockDim.x) {
    if (idx < NA) {
      int c = idx & 255; int r = idx >> 8;
      int q = r % P_; int p = (r / P_) % P_; int b = r / PP_;
      inarr[idx] = cand[((b * 256 + c) * P_ + p) * P_ + q];
    } else if (idx < NA + NB) {
      int t = idx - NA;
      int c = t & 255; int r = t >> 8;
      int j = r % S_; int i = (r / S_) % S_; int b = r / SS_;
      inarr[idx] = templ[((b * 256 + c) * S_ + i) * S_ + j];
    } else if (idx < NA + NB + NW0H) {
      int t = idx - NA - NB;
      int m = t >> 8; int c = t & 255;
      // rows 0..255 = conv1 weights (w0[:,256:]); rows 256..511 = g weights (w0[:,:256])
      w0h[t] = (half_t)(m < 256 ? w0[m * 512 + 256 + c] : w0[(m - 256) * 512 + c]);
    } else {
      int t = idx - NA - NB - NW0H;
      if (t < 32768)      w1h[t] = (half_t)w1[t];                  // [128][256]
      else if (t < 40960) w2h[t - 32768] = (half_t)w2[t - 32768];  // [64][128]
      else                w3h[t - 40960] = (half_t)w3[t - 40960];  // [32][64]
    }
  }
}

// ---------------------------------------------------------------------------
// layer-0 GEMM via MFMA: out0[row][m] = sum_c w0h[m][c] * in[row][c], m<512
// block = 16 rows, 512 threads (8 waves x 4 m-tiles of 16 out-ch)
// ---------------------------------------------------------------------------
__global__ __launch_bounds__(512) void l0gemm_kernel(
    const float* __restrict__ in, const half_t* __restrict__ w0h,
    float* __restrict__ out0)
{
  __shared__ __align__(16) char xls[16 * 512];   // [16 rows][256ch] f16 swz
  const int tid  = threadIdx.x;
  const int lane = tid & 63;
  const int wvs  = tid >> 6;
  const int row0 = blockIdx.x * 16;

  // stage 16 rows of input as f16 (swizzled)
  {
    const int row = tid >> 5;
    const int c8  = (tid & 31) * 8;
    const float* src = in + (size_t)(row0 + row) * 256 + c8;
    half8 h;
#pragma unroll
    for (int r = 0; r < 8; ++r) h[r] = (half_t)src[r];
    const int off = (row * 512 + c8 * 2) ^ ((row & 7) << 4);
    *(half8*)(xls + off) = h;
  }
  __syncthreads();

  const int l15 = lane & 15, g = lane >> 4;
  f32x4 acc[4];
#pragma unroll
  for (int mt = 0; mt < 4; ++mt) acc[mt] = (f32x4){0.f, 0.f, 0.f, 0.f};
#pragma unroll 2
  for (int kb = 0; kb < 8; ++kb) {
    const int off = (l15 * 512 + kb * 64 + g * 16) ^ ((l15 & 7) << 4);
    half8 bfr = *(const half8*)(xls + off);
#pragma unroll
    for (int mt = 0; mt < 4; ++mt) {
      const half_t* ap = w0h + (size_t)((wvs * 4 + mt) * 16 + l15) * 256 + kb * 32 + g * 8;
      half8 a = *(const half8*)ap;
      acc[mt] = __builtin_amdgcn_mfma_f32_16x16x32_f16(a, bfr, acc[mt], 0, 0, 0);
    }
  }
#pragma unroll
  for (int mt = 0; mt < 4; ++mt) {
    const int m0c = (wvs * 4 + mt) * 16 + g * 4;
    *(f32x4*)(out0 + (size_t)(row0 + l15) * 512 + m0c) = acc[mt];
  }
}

// ---------------------------------------------------------------------------
__global__ __launch_bounds__(256) void rowsum_kernel(
    const float* __restrict__ out0, float* __restrict__ rows)
{
  const int bid = blockIdx.x;
  const int o = threadIdx.x;
  const int v = bid % 17; const int p = (bid / 17) % 31; const int b = bid / (17 * 31);
  float s = 0.f;
  for (int j = 0; j < 15; ++j)
    s += out0[(size_t)(b * PP_ + p * P_ + v + j) * 512 + 256 + o];
  rows[(size_t)bid * 256 + o] = s;
}

__global__ __launch_bounds__(256) void colsum_kernel(
    const float* __restrict__ rows, float* __restrict__ m0v)
{
  const int bid = blockIdx.x;
  const int o = threadIdx.x;
  const int v = bid % 17; const int u = (bid / 17) % 17; const int b = bid / KK_;
  float s = 0.f;
  for (int i = 0; i < 15; ++i)
    s += rows[(size_t)((b * 31 + u + i) * 17 + v) * 256 + o];
  m0v[(size_t)bid * 256 + o] = s * (1.0f / 225.0f);
}

__global__ __launch_bounds__(256) void tmean0_kernel(
    const float* __restrict__ out0, float* __restrict__ tm0v)
{
  const int b = blockIdx.x;
  const int o = threadIdx.x;
  float s = 0.f;
  for (int t = 0; t < SS_; ++t)
    s += out0[(size_t)(NROW_C + b * SS_ + t) * 512 + 256 + o];
  tm0v[b * 256 + o] = s * (1.0f / 225.0f);
}

// ---------------------------------------------------------------------------
__global__ __launch_bounds__(512, 4) void chain_kernel(
    const float* __restrict__ out0, const float* __restrict__ m0v,
    const float* __restrict__ tm0v,
    const half_t* __restrict__ w1h, const half_t* __restrict__ w2h,
    const half_t* __restrict__ w3h,
    const float* __restrict__ w4, const float* __restrict__ w5,
    const float* __restrict__ w6,
    const float* __restrict__ inarr, float* __restrict__ out)
{
  __shared__ __align__(16) char lds[LDSB];
  float* ldsf = (float*)lds;
  float* sm   = (float*)(lds + SMB);
  float* red  = (float*)(lds + REDB);

  const int tid  = threadIdx.x;
  const int lane = tid & 63;
  const int wvs  = __builtin_amdgcn_readfirstlane(tid >> 6);
  const int bid  = (blockIdx.x & 7) * 290 + (blockIdx.x >> 3);   // XCD swizzle (2320 = 8*290)
  const bool is_t = (bid >= B_ * KK_);
  int b, u = 0, v = 0;
  const float* mean_vec;
  if (!is_t) {
    b = bid / KK_;
    int r = bid % KK_;
    u = r / K_; v = r % K_;
    mean_vec = m0v + (size_t)bid * 256;
  } else {
    b = bid - B_ * KK_;
    mean_vec = tm0v + (size_t)b * 256;
  }

  // one-time LDS weight staging (persistent region, above x1 span)
  ((float*)(lds + W4B))[(tid >> 5) * 36 + (tid & 31)] = w4[tid];       // [16][36f]
  if (tid < 128) ((float*)(lds + W5B))[(tid >> 4) * 20 + (tid & 15)] = w5[tid]; // [8][20f]
  if (tid < 8)   ((float*)(lds + W6B))[tid] = w6[tid];

  // W1 fragment base (streamed per half-tile — not hoisted)
  const half_t* w1base = w1h + (size_t)(16 * wvs + (lane & 15)) * 256 + ((lane >> 4) << 3);
  const int g2 = wvs & 3, h2 = wvs >> 2;
  half8 af2[4];
  {
    const half_t* base = w2h + (size_t)(16 * g2 + (lane & 15)) * 128 + ((lane >> 4) << 3);
#pragma unroll
    for (int kb = 0; kb < 4; ++kb) af2[kb] = *(const half8*)(base + kb * 32);
  }
  const int rt3 = wvs & 1, ct3 = wvs >> 1;
  const half_t* b3ptr = w3h + (size_t)(16 * rt3 + (lane & 15)) * 64 + ((lane >> 4) << 3);
  // mean vector split by K-half (lane covers 32 ch-quads per half)
  const int l31 = lane & 31, lhi = lane >> 5;
  const f32x4 mv4a = *(const f32x4*)(mean_vec + 4 * l31);
  const f32x4 mv4b = *(const f32x4*)(mean_vec + 128 + 4 * l31);

  for (int ti = 0; ti < 4; ++ti) {
    const int s0 = ti * 64;
    const int cnt = min(64, SS_ - s0);

    // ---- layer 1 over two K-halves; x0 half-buffer reused
    f32x4 acc[4];
#pragma unroll
    for (int nt = 0; nt < 4; ++nt) acc[nt] = (f32x4){0.f, 0.f, 0.f, 0.f};
#pragma unroll
    for (int h = 0; h < 2; ++h) {
      // stage x0 half-K: [pos][128ch] f16 swz
      const f32x4 mvh = h ? mv4b : mv4a;
      for (int tt = 0; tt < 4; ++tt) {
        const int pos = 2 * (wvs + tt * 8) + lhi;
        int s = min(s0 + pos, SS_ - 1);
        size_t row;
        if (!is_t) { int i = s / 15, j = s - i * 15; row = (size_t)(b * PP_ + (u + i) * P_ + (v + j)); }
        else       { row = (size_t)(NROW_C + b * SS_ + s); }
        f32x4 x = *(const f32x4*)(out0 + row * 512 + h * 128 + 4 * l31);
        half4 hh;
#pragma unroll
        for (int r = 0; r < 4; ++r) {
          float a = x[r] + mvh[r];
          a = fmaxf(a, 0.01f * a);
          hh[r] = (half_t)a;
        }
        const int off = (pos * 256 + l31 * 8) ^ ((pos & 7) << 4);
        *(half4*)(lds + X0B + off) = hh;
      }
      __syncthreads();

      {
        const half_t* w1p = w1base;
        asm volatile("" : "+v"(w1p));   // defeat hoisting across tiles
#pragma unroll 2
        for (int kbp = 0; kbp < 4; ++kbp) {
          half8 a1 = *(const half8*)(w1p + (h * 4 + kbp) * 32);
          const int kbyte = kbp * 64 + ((lane >> 4) << 4);
#pragma unroll
          for (int nt = 0; nt < 4; ++nt) {
            const int pos = nt * 16 + (lane & 15);
            const int off = (pos * 256 + kbyte) ^ ((pos & 7) << 4);
            half8 bfr = *(const half8*)(lds + X0B + off);
            acc[nt] = __builtin_amdgcn_mfma_f32_16x16x32_f16(a1, bfr, acc[nt], 0, 0, 0);
          }
        }
      }
      if (h == 1) {
        // epilogue -> x1 f16 [pos][128ch] swz
#pragma unroll
        for (int nt = 0; nt < 4; ++nt) {
          const int pos = nt * 16 + (lane & 15);
          half4 hh;
#pragma unroll
          for (int r = 0; r < 4; ++r) {
            float a = acc[nt][r];
            a = fmaxf(a, 0.01f * a);
            hh[r] = (half_t)a;
          }
          const int ch0 = 16 * wvs + ((lane >> 4) << 2);
          const int off = (pos * 256 + ch0 * 2) ^ ((pos & 7) << 4);
          *(half4*)(lds + X1B + off) = hh;
        }
      }
      __syncthreads();
    }

    // ---- layer 2: 128 -> 64 MFMA; epilogue -> x2 f16 [pos][64ch] swz (X0 region)
    f32x4 acc2[2];
#pragma unroll
    for (int nt = 0; nt < 2; ++nt) acc2[nt] = (f32x4){0.f, 0.f, 0.f, 0.f};
#pragma unroll
    for (int kb = 0; kb < 4; ++kb) {
      const int kbyte = kb * 64 + ((lane >> 4) << 4);
#pragma unroll
      for (int nt = 0; nt < 2; ++nt) {
        const int pos = h2 * 32 + nt * 16 + (lane & 15);
        const int off = (pos * 256 + kbyte) ^ ((pos & 7) << 4);
        half8 bfr = *(const half8*)(lds + X1B + off);
        acc2[nt] = __builtin_amdgcn_mfma_f32_16x16x32_f16(af2[kb], bfr, acc2[nt], 0, 0, 0);
      }
    }
#pragma unroll
    for (int nt = 0; nt < 2; ++nt) {
      const int pos = h2 * 32 + nt * 16 + (lane & 15);
      const int ch0 = 16 * g2 + ((lane >> 4) << 2);
      half4 hh;
#pragma unroll
      for (int r = 0; r < 4; ++r) {
        float a = acc2[nt][r];
        a = fmaxf(a, 0.01f * a);
        hh[r] = (half_t)a;
      }
      const int off = (pos * 128 + ch0 * 2) ^ ((pos & 7) << 4);
      *(half4*)(lds + X0B + off) = hh;
    }
    __syncthreads();

    // ---- layer 3: 64 -> 32 MFMA; epilogue -> x3T f32 [pos][36f] (alias dead x1)
    {
      f32x4 acc3 = (f32x4){0.f, 0.f, 0.f, 0.f};
      const int pos = ct3 * 16 + (lane & 15);
#pragma unroll
      for (int kb = 0; kb < 2; ++kb) {
        half8 a3 = *(const half8*)(b3ptr + kb * 32);
        const int kbyte = kb * 64 + ((lane >> 4) << 4);
        const int off = (pos * 128 + kbyte) ^ ((pos & 7) << 4);
        half8 bfr = *(const half8*)(lds + X0B + off);
        acc3 = __builtin_amdgcn_mfma_f32_16x16x32_f16(a3, bfr, acc3, 0, 0, 0);
      }
      const int ch0 = 16 * rt3 + ((lane >> 4) << 2);
      f32x4 o4;
#pragma unroll
      for (int r = 0; r < 4; ++r) {
        float a = acc3[r];
        o4[r] = fmaxf(a, 0.01f * a);
      }
      *(f32x4*)(lds + X3TB + pos * 144 + ch0 * 4) = o4;
    }
    __syncthreads();

    // ---- layers 4-6, pos-sliced per wave (pos 8*wvs..+7), barrier-free
    {
      const int p = lane >> 3, g = lane & 7;
      const int pos = 8 * wvs + p;
      float a4_0 = 0.f, a4_1 = 0.f;
#pragma unroll
      for (int c0 = 0; c0 < 32; c0 += 4) {
        f32x4 x  = *(const f32x4*)(lds + X3TB + pos * 144 + c0 * 4);
        f32x4 wA = *(const f32x4*)(lds + W4B + (2 * g) * 144 + c0 * 4);
        f32x4 wB = *(const f32x4*)(lds + W4B + (2 * g + 1) * 144 + c0 * 4);
#pragma unroll
        for (int r = 0; r < 4; ++r) {
          a4_0 = fmaf(wA[r], x[r], a4_0);
          a4_1 = fmaf(wB[r], x[r], a4_1);
        }
      }
      f32x2 y4v;
      y4v[0] = fmaxf(a4_0, 0.01f * a4_0);
      y4v[1] = fmaxf(a4_1, 0.01f * a4_1);
      *(f32x2*)(lds + Y4B + pos * 80 + g * 8) = y4v;
      float a5 = 0.f;
#pragma unroll
      for (int c0 = 0; c0 < 16; c0 += 4) {
        f32x4 x = *(const f32x4*)(lds + Y4B + pos * 80 + c0 * 4);
        f32x4 w = *(const f32x4*)(lds + W5B + g * 80 + c0 * 4);
#pragma unroll
        for (int r = 0; r < 4; ++r) a5 = fmaf(w[r], x[r], a5);
      }
      a5 = fmaxf(a5, 0.01f * a5);
      float t6 = ((float*)(lds + W6B))[g] * a5;
      t6 += __shfl_xor(t6, 1);
      t6 += __shfl_xor(t6, 2);
      t6 += __shfl_xor(t6, 4);
      if (g == 0 && (8 * wvs + p) < cnt) sm[s0 + pos] = t6;
    }
    __syncthreads();
  }

  // ---- softmax over 225 logits
  float vv = (tid < SS_) ? sm[tid] : -1e30f;
  float m = vv;
#pragma unroll
  for (int off = 32; off >= 1; off >>= 1) m = fmaxf(m, __shfl_xor(m, off));
  if (lane == 0) red[wvs] = m;
  __syncthreads();
  m = red[0];
#pragma unroll
  for (int w = 1; w < 8; ++w) m = fmaxf(m, red[w]);
  float e = (tid < SS_) ? __expf(vv - m) : 0.f;
  float ss = e;
#pragma unroll
  for (int off = 32; off >= 1; off >>= 1) ss += __shfl_xor(ss, off);
  __syncthreads();
  if (lane == 0) red[wvs] = ss;
  __syncthreads();
  float Stot = red[0];
#pragma unroll
  for (int w = 1; w < 8; ++w) Stot += red[w];
  if (tid < SS_) sm[tid] = e / Stot;
  __syncthreads();

  // ---- weighted channel sum over raw features
  const int c_st = tid & 255;
  const int h_st = tid >> 8;
  float acc3 = 0.f;
  if (!is_t) {
    for (int s = h_st; s < SS_; s += 2) {
      int i = s / 15, j = s - i * 15;
      size_t row = (size_t)b * PP_ + (u + i) * P_ + (v + j);
      acc3 = fmaf(sm[s], inarr[row * 256 + c_st], acc3);
    }
  } else {
    for (int s = h_st; s < SS_; s += 2)
      acc3 = fmaf(sm[s], inarr[(size_t)(NROW_C + b * SS_ + s) * 256 + c_st], acc3);
  }
  __syncthreads();
  ldsf[tid] = acc3;
  __syncthreads();
  if (tid < 256) {
    float tot = ldsf[tid] + ldsf[256 + tid];
    if (!is_t) out[2048 + ((size_t)(b * 256 + tid) * 17 + u) * 17 + v] = tot;
    else       out[b * 256 + tid] = tot;
  }
}

// ---------------------------------------------------------------------------
extern "C" void kernel_launch(void* const* d_in, const int* in_sizes, int n_in,
                              void* d_out, int out_size, void* d_ws, size_t ws_size,
                              hipStream_t stream)
{
  const float* templ = (const float*)d_in[0];
  const float* cand  = (const float*)d_in[1];
  const float* w0 = (const float*)d_in[2];
  const float* w1 = (const float*)d_in[3];
  const float* w2 = (const float*)d_in[4];
  const float* w3 = (const float*)d_in[5];
  const float* w4 = (const float*)d_in[6];
  const float* w5 = (const float*)d_in[7];
  const float* w6 = (const float*)d_in[8];

  float* ws    = (float*)d_ws;
  float* inarr = ws + OFF_IN;
  float* out0  = ws + OFF_OUT0;
  float* rows  = ws + OFF_ROWS;
  float* m0v   = ws + OFF_M0;
  float* tm0v  = ws + OFF_TM0;
  half_t* w0h  = (half_t*)(ws + OFF_F16);
  half_t* w1h  = w0h + NW0H;
  half_t* w2h  = w1h + 128 * 256;
  half_t* w3h  = w2h + 64 * 128;
  float* outf  = (float*)d_out;

  prep_kernel<<<2048, 256, 0, stream>>>(templ, cand, w0, w1, w2, w3,
                                        inarr, w0h, w1h, w2h, w3h);
  l0gemm_kernel<<<NROW / 16, 512, 0, stream>>>(inarr, w0h, out0);
  rowsum_kernel<<<B_ * 31 * 17, 256, 0, stream>>>(out0, rows);
  colsum_kernel<<<B_ * KK_, 256, 0, stream>>>(rows, m0v);
  tmean0_kernel<<<B_, 256, 0, stream>>>(out0, tm0v);
  chain_kernel<<<B_ * KK_ + B_, 512, 0, stream>>>(out0, m0v, tm0v,
                                                  w1h, w2h, w3h, w4, w5, w6,
                                                  inarr, outf);
}

// Round 15
// 302.189 us; speedup vs baseline: 1.6496x; 1.1570x over previous
//
#include <hip/hip_runtime.h>

typedef _Float16 half_t;
typedef half_t half4 __attribute__((ext_vector_type(4)));
typedef half_t half8 __attribute__((ext_vector_type(8)));
typedef __fp16 pk16x2 __attribute__((ext_vector_type(2)));
typedef float  f32x4 __attribute__((ext_vector_type(4)));
typedef float  f32x2 __attribute__((ext_vector_type(2)));

static __device__ __forceinline__ half4 pack4(f32x4 a) {
  pk16x2 lo = __builtin_amdgcn_cvt_pkrtz(a[0], a[1]);
  pk16x2 hi = __builtin_amdgcn_cvt_pkrtz(a[2], a[3]);
  half4 h;
  h[0] = lo[0]; h[1] = lo[1]; h[2] = hi[0]; h[3] = hi[1];
  return h;
}

constexpr int B_  = 8;
constexpr int S_  = 15;
constexpr int K_  = 17;
constexpr int P_  = 31;
constexpr int SS_ = 225;
constexpr int PP_ = 961;
constexpr int KK_ = 289;

constexpr int NROW_C = B_ * PP_;          // 7688
constexpr int NROW_T = B_ * SS_;          // 1800
constexpr int NROW   = NROW_C + NROW_T;   // 9488 = 593*16

constexpr int NW0H = 512 * 256;                   // w0h f16 (conv1 rows | g rows)
constexpr int NF16 = 128*256 + 64*128 + 32*64;    // w1h | w2h | w3h

// workspace float offsets
constexpr size_t OFF_IN   = 0;
constexpr size_t OFF_OUT0 = OFF_IN   + (size_t)NROW * 256;
constexpr size_t OFF_ROWS = OFF_OUT0 + (size_t)NROW * 512;
constexpr size_t OFF_M0   = OFF_ROWS + (size_t)B_ * 31 * 17 * 256;
constexpr size_t OFF_TM0  = OFF_M0   + (size_t)B_ * KK_ * 256;
constexpr size_t OFF_F16  = OFF_TM0  + (size_t)B_ * 256;   // f16 arena

// chain LDS byte offsets
constexpr int X0B  = 0;
constexpr int X1B  = 16384;
constexpr int X3TB = 16384;   // f32 x3T [64][36f] (alias dead x1)
constexpr int Y4B  = 25600;   // f32 y4T [64][20f] (alias dead x1)
// persistent (must NOT overlap x1's 16384..32768 span):
constexpr int SMB  = 32768;   // 240 f logits
constexpr int REDB = 33728;   // 16 f
constexpr int W4B  = 33792;   // w4 [16][36f] (2304 B)
constexpr int W5B  = 36096;   // w5 [8][20f]  (640 B)
constexpr int W6B  = 36736;   // w6 [8] (32 B)
constexpr int ROWB = 36768;   // 225 u16 row table (456 B w/ pad)
constexpr int LDSB = 37248;

// ---------------------------------------------------------------------------
__global__ __launch_bounds__(256) void prep_kernel(
    const float* __restrict__ templ, const float* __restrict__ cand,
    const float* __restrict__ w0, const float* __restrict__ w1,
    const float* __restrict__ w2, const float* __restrict__ w3,
    float* __restrict__ inarr, half_t* __restrict__ w0h,
    half_t* __restrict__ w1h, half_t* __restrict__ w2h,
    half_t* __restrict__ w3h)
{
  const int NA = NROW_C * 256;
  const int NB = NROW_T * 256;
  const int total = NA + NB + NW0H + NF16;
  for (int idx = blockIdx.x * blockDim.x + threadIdx.x; idx < total;
       idx += gridDim.x * blockDim.x) {
    if (idx < NA) {
      int c = idx & 255; int r = idx >> 8;
      int q = r % P_; int p = (r / P_) % P_; int b = r / PP_;
      inarr[idx] = cand[((b * 256 + c) * P_ + p) * P_ + q];
    } else if (idx < NA + NB) {
      int t = idx - NA;
      int c = t & 255; int r = t >> 8;
      int j = r % S_; int i = (r / S_) % S_; int b = r / SS_;
      inarr[idx] = templ[((b * 256 + c) * S_ + i) * S_ + j];
    } else if (idx < NA + NB + NW0H) {
      int t = idx - NA - NB;
      int m = t >> 8; int c = t & 255;
      // rows 0..255 = conv1 weights (w0[:,256:]); rows 256..511 = g weights (w0[:,:256])
      w0h[t] = (half_t)(m < 256 ? w0[m * 512 + 256 + c] : w0[(m - 256) * 512 + c]);
    } else {
      int t = idx - NA - NB - NW0H;
      if (t < 32768)      w1h[t] = (half_t)w1[t];                  // [128][256]
      else if (t < 40960) w2h[t - 32768] = (half_t)w2[t - 32768];  // [64][128]
      else                w3h[t - 40960] = (half_t)w3[t - 40960];  // [32][64]
    }
  }
}

// ---------------------------------------------------------------------------
// layer-0 GEMM via MFMA: out0[row][m] = sum_c w0h[m][c] * in[row][c], m<512
// ---------------------------------------------------------------------------
__global__ __launch_bounds__(512) void l0gemm_kernel(
    const float* __restrict__ in, const half_t* __restrict__ w0h,
    float* __restrict__ out0)
{
  __shared__ __align__(16) char xls[16 * 512];   // [16 rows][256ch] f16 swz
  const int tid  = threadIdx.x;
  const int lane = tid & 63;
  const int wvs  = tid >> 6;
  const int row0 = blockIdx.x * 16;

  {
    const int row = tid >> 5;
    const int c8  = (tid & 31) * 8;
    const float* src = in + (size_t)(row0 + row) * 256 + c8;
    half8 h;
#pragma unroll
    for (int r = 0; r < 8; ++r) h[r] = (half_t)src[r];
    const int off = (row * 512 + c8 * 2) ^ ((row & 7) << 4);
    *(half8*)(xls + off) = h;
  }
  __syncthreads();

  const int l15 = lane & 15, g = lane >> 4;
  f32x4 acc[4];
#pragma unroll
  for (int mt = 0; mt < 4; ++mt) acc[mt] = (f32x4){0.f, 0.f, 0.f, 0.f};
#pragma unroll 2
  for (int kb = 0; kb < 8; ++kb) {
    const int off = (l15 * 512 + kb * 64 + g * 16) ^ ((l15 & 7) << 4);
    half8 bfr = *(const half8*)(xls + off);
#pragma unroll
    for (int mt = 0; mt < 4; ++mt) {
      const half_t* ap = w0h + (size_t)((wvs * 4 + mt) * 16 + l15) * 256 + kb * 32 + g * 8;
      half8 a = *(const half8*)ap;
      acc[mt] = __builtin_amdgcn_mfma_f32_16x16x32_f16(a, bfr, acc[mt], 0, 0, 0);
    }
  }
#pragma unroll
  for (int mt = 0; mt < 4; ++mt) {
    const int m0c = (wvs * 4 + mt) * 16 + g * 4;
    *(f32x4*)(out0 + (size_t)(row0 + l15) * 512 + m0c) = acc[mt];
  }
}

// ---------------------------------------------------------------------------
__global__ __launch_bounds__(256) void rowsum_kernel(
    const float* __restrict__ out0, float* __restrict__ rows)
{
  const int bid = blockIdx.x;
  const int o = threadIdx.x;
  const int v = bid % 17; const int p = (bid / 17) % 31; const int b = bid / (17 * 31);
  float s = 0.f;
  for (int j = 0; j < 15; ++j)
    s += out0[(size_t)(b * PP_ + p * P_ + v + j) * 512 + 256 + o];
  rows[(size_t)bid * 256 + o] = s;
}

__global__ __launch_bounds__(256) void colsum_kernel(
    const float* __restrict__ rows, float* __restrict__ m0v)
{
  const int bid = blockIdx.x;
  const int o = threadIdx.x;
  const int v = bid % 17; const int u = (bid / 17) % 17; const int b = bid / KK_;
  float s = 0.f;
  for (int i = 0; i < 15; ++i)
    s += rows[(size_t)((b * 31 + u + i) * 17 + v) * 256 + o];
  m0v[(size_t)bid * 256 + o] = s * (1.0f / 225.0f);
}

__global__ __launch_bounds__(256) void tmean0_kernel(
    const float* __restrict__ out0, float* __restrict__ tm0v)
{
  const int b = blockIdx.x;
  const int o = threadIdx.x;
  float s = 0.f;
  for (int t = 0; t < SS_; ++t)
    s += out0[(size_t)(NROW_C + b * SS_ + t) * 512 + 256 + o];
  tm0v[b * 256 + o] = s * (1.0f / 225.0f);
}

// ---------------------------------------------------------------------------
__global__ __launch_bounds__(512, 4) void chain_kernel(
    const float* __restrict__ out0, const float* __restrict__ m0v,
    const float* __restrict__ tm0v,
    const half_t* __restrict__ w1h, const half_t* __restrict__ w2h,
    const half_t* __restrict__ w3h,
    const float* __restrict__ w4, const float* __restrict__ w5,
    const float* __restrict__ w6,
    const float* __restrict__ inarr, float* __restrict__ out)
{
  __shared__ __align__(16) char lds[LDSB];
  float*    ldsf   = (float*)lds;
  float*    sm     = (float*)(lds + SMB);
  float*    red    = (float*)(lds + REDB);
  uint16_t* rowoff = (uint16_t*)(lds + ROWB);

  const int tid  = threadIdx.x;
  const int lane = tid & 63;
  const int wvs  = __builtin_amdgcn_readfirstlane(tid >> 6);
  const int bid  = (blockIdx.x & 7) * 290 + (blockIdx.x >> 3);   // XCD swizzle (2320 = 8*290)
  const bool is_t = (bid >= B_ * KK_);
  int b, u = 0, v = 0;
  const float* mean_vec;
  if (!is_t) {
    b = bid / KK_;
    int r = bid % KK_;
    u = r / K_; v = r % K_;
    mean_vec = m0v + (size_t)bid * 256;
  } else {
    b = bid - B_ * KK_;
    mean_vec = tm0v + (size_t)b * 256;
  }

  // one-time LDS staging: row table + small weights (persistent region)
  if (tid < SS_) {
    int i = tid / 15, j = tid - i * 15;
    rowoff[tid] = is_t ? (uint16_t)(NROW_C + b * SS_ + tid)
                       : (uint16_t)(b * PP_ + (u + i) * P_ + (v + j));
  }
  ((float*)(lds + W4B))[(tid >> 5) * 36 + (tid & 31)] = w4[tid];       // [16][36f]
  if (tid < 128) ((float*)(lds + W5B))[(tid >> 4) * 20 + (tid & 15)] = w5[tid]; // [8][20f]
  if (tid < 8)   ((float*)(lds + W6B))[tid] = w6[tid];

  // W1 fragment base (streamed per half-tile — not hoisted)
  const half_t* w1base = w1h + (size_t)(16 * wvs + (lane & 15)) * 256 + ((lane >> 4) << 3);
  const int g2 = wvs & 3, h2 = wvs >> 2;
  half8 af2[4];
  {
    const half_t* base = w2h + (size_t)(16 * g2 + (lane & 15)) * 128 + ((lane >> 4) << 3);
#pragma unroll
    for (int kb = 0; kb < 4; ++kb) af2[kb] = *(const half8*)(base + kb * 32);
  }
  const int rt3 = wvs & 1, ct3 = wvs >> 1;
  const half_t* b3ptr = w3h + (size_t)(16 * rt3 + (lane & 15)) * 64 + ((lane >> 4) << 3);
  const int l31 = lane & 31, lhi = lane >> 5;
  const f32x4 mv4a = *(const f32x4*)(mean_vec + 4 * l31);
  const f32x4 mv4b = *(const f32x4*)(mean_vec + 128 + 4 * l31);
  __syncthreads();   // rowoff/table visibility before staging reads it

  for (int ti = 0; ti < 4; ++ti) {
    const int s0 = ti * 64;
    const int cnt = min(64, SS_ - s0);

    // ---- layer 1 over two K-halves; x0 half-buffer reused
    f32x4 acc[4];
#pragma unroll
    for (int nt = 0; nt < 4; ++nt) acc[nt] = (f32x4){0.f, 0.f, 0.f, 0.f};
#pragma unroll
    for (int h = 0; h < 2; ++h) {
      // stage x0 half-K: [pos][128ch] f16 swz, via rowoff table
      const f32x4 mvh = h ? mv4b : mv4a;
      for (int tt = 0; tt < 4; ++tt) {
        const int pos = 2 * (wvs + tt * 8) + lhi;
        const int srow = rowoff[min(s0 + pos, SS_ - 1)];
        f32x4 x = *(const f32x4*)(out0 + ((size_t)srow << 9) + h * 128 + 4 * l31);
        f32x4 a;
#pragma unroll
        for (int r = 0; r < 4; ++r) {
          float t2 = x[r] + mvh[r];
          a[r] = fmaxf(t2, 0.01f * t2);
        }
        const int off = (pos * 256 + l31 * 8) ^ ((pos & 7) << 4);
        *(half4*)(lds + X0B + off) = pack4(a);
      }
      __syncthreads();

      {
        const half_t* w1p = w1base;
        asm volatile("" : "+v"(w1p));   // defeat hoisting across tiles
#pragma unroll 2
        for (int kbp = 0; kbp < 4; ++kbp) {
          half8 a1 = *(const half8*)(w1p + (h * 4 + kbp) * 32);
          const int kbyte = kbp * 64 + ((lane >> 4) << 4);
#pragma unroll
          for (int nt = 0; nt < 4; ++nt) {
            const int pos = nt * 16 + (lane & 15);
            const int off = (pos * 256 + kbyte) ^ ((pos & 7) << 4);
            half8 bfr = *(const half8*)(lds + X0B + off);
            acc[nt] = __builtin_amdgcn_mfma_f32_16x16x32_f16(a1, bfr, acc[nt], 0, 0, 0);
          }
        }
      }
      if (h == 1) {
#pragma unroll
        for (int nt = 0; nt < 4; ++nt) {
          const int pos = nt * 16 + (lane & 15);
          f32x4 a;
#pragma unroll
          for (int r = 0; r < 4; ++r) a[r] = fmaxf(acc[nt][r], 0.01f * acc[nt][r]);
          const int ch0 = 16 * wvs + ((lane >> 4) << 2);
          const int off = (pos * 256 + ch0 * 2) ^ ((pos & 7) << 4);
          *(half4*)(lds + X1B + off) = pack4(a);
        }
      }
      __syncthreads();
    }

    // ---- layer 2: 128 -> 64 MFMA; epilogue -> x2 f16 [pos][64ch] swz (X0 region)
    f32x4 acc2[2];
#pragma unroll
    for (int nt = 0; nt < 2; ++nt) acc2[nt] = (f32x4){0.f, 0.f, 0.f, 0.f};
#pragma unroll
    for (int kb = 0; kb < 4; ++kb) {
      const int kbyte = kb * 64 + ((lane >> 4) << 4);
#pragma unroll
      for (int nt = 0; nt < 2; ++nt) {
        const int pos = h2 * 32 + nt * 16 + (lane & 15);
        const int off = (pos * 256 + kbyte) ^ ((pos & 7) << 4);
        half8 bfr = *(const half8*)(lds + X1B + off);
        acc2[nt] = __builtin_amdgcn_mfma_f32_16x16x32_f16(af2[kb], bfr, acc2[nt], 0, 0, 0);
      }
    }
#pragma unroll
    for (int nt = 0; nt < 2; ++nt) {
      const int pos = h2 * 32 + nt * 16 + (lane & 15);
      const int ch0 = 16 * g2 + ((lane >> 4) << 2);
      f32x4 a;
#pragma unroll
      for (int r = 0; r < 4; ++r) a[r] = fmaxf(acc2[nt][r], 0.01f * acc2[nt][r]);
      const int off = (pos * 128 + ch0 * 2) ^ ((pos & 7) << 4);
      *(half4*)(lds + X0B + off) = pack4(a);
    }
    __syncthreads();

    // ---- layer 3: 64 -> 32 MFMA; epilogue -> x3T f32 [pos][36f] (alias dead x1)
    {
      f32x4 acc3 = (f32x4){0.f, 0.f, 0.f, 0.f};
      const int pos = ct3 * 16 + (lane & 15);
#pragma unroll
      for (int kb = 0; kb < 2; ++kb) {
        half8 a3 = *(const half8*)(b3ptr + kb * 32);
        const int kbyte = kb * 64 + ((lane >> 4) << 4);
        const int off = (pos * 128 + kbyte) ^ ((pos & 7) << 4);
        half8 bfr = *(const half8*)(lds + X0B + off);
        acc3 = __builtin_amdgcn_mfma_f32_16x16x32_f16(a3, bfr, acc3, 0, 0, 0);
      }
      const int ch0 = 16 * rt3 + ((lane >> 4) << 2);
      f32x4 o4;
#pragma unroll
      for (int r = 0; r < 4; ++r) o4[r] = fmaxf(acc3[r], 0.01f * acc3[r]);
      *(f32x4*)(lds + X3TB + pos * 144 + ch0 * 4) = o4;
    }
    __syncthreads();

    // ---- layers 4-6, pos-sliced per wave (pos 8*wvs..+7), barrier-free
    {
      const int p = lane >> 3, g = lane & 7;
      const int pos = 8 * wvs + p;
      float a4_0 = 0.f, a4_1 = 0.f;
#pragma unroll
      for (int c0 = 0; c0 < 32; c0 += 4) {
        f32x4 x  = *(const f32x4*)(lds + X3TB + pos * 144 + c0 * 4);
        f32x4 wA = *(const f32x4*)(lds + W4B + (2 * g) * 144 + c0 * 4);
        f32x4 wB = *(const f32x4*)(lds + W4B + (2 * g + 1) * 144 + c0 * 4);
#pragma unroll
        for (int r = 0; r < 4; ++r) {
          a4_0 = fmaf(wA[r], x[r], a4_0);
          a4_1 = fmaf(wB[r], x[r], a4_1);
        }
      }
      f32x2 y4v;
      y4v[0] = fmaxf(a4_0, 0.01f * a4_0);
      y4v[1] = fmaxf(a4_1, 0.01f * a4_1);
      *(f32x2*)(lds + Y4B + pos * 80 + g * 8) = y4v;
      float a5 = 0.f;
#pragma unroll
      for (int c0 = 0; c0 < 16; c0 += 4) {
        f32x4 x = *(const f32x4*)(lds + Y4B + pos * 80 + c0 * 4);
        f32x4 w = *(const f32x4*)(lds + W5B + g * 80 + c0 * 4);
#pragma unroll
        for (int r = 0; r < 4; ++r) a5 = fmaf(w[r], x[r], a5);
      }
      a5 = fmaxf(a5, 0.01f * a5);
      float t6 = ((float*)(lds + W6B))[g] * a5;
      t6 += __shfl_xor(t6, 1);
      t6 += __shfl_xor(t6, 2);
      t6 += __shfl_xor(t6, 4);
      if (g == 0 && (8 * wvs + p) < cnt) sm[s0 + pos] = t6;
    }
    __syncthreads();
  }

  // ---- softmax over 225 logits
  float vv = (tid < SS_) ? sm[tid] : -1e30f;
  float m = vv;
#pragma unroll
  for (int off = 32; off >= 1; off >>= 1) m = fmaxf(m, __shfl_xor(m, off));
  if (lane == 0) red[wvs] = m;
  __syncthreads();
  m = red[0];
#pragma unroll
  for (int w = 1; w < 8; ++w) m = fmaxf(m, red[w]);
  float e = (tid < SS_) ? __expf(vv - m) : 0.f;
  float ss = e;
#pragma unroll
  for (int off = 32; off >= 1; off >>= 1) ss += __shfl_xor(ss, off);
  __syncthreads();
  if (lane == 0) red[wvs] = ss;
  __syncthreads();
  float Stot = red[0];
#pragma unroll
  for (int w = 1; w < 8; ++w) Stot += red[w];
  if (tid < SS_) sm[tid] = e / Stot;
  __syncthreads();

  // ---- weighted channel sum: 2 channels/thread, 4-way position split
  {
    const int c2 = (tid & 127) * 2;
    const int q  = tid >> 7;          // 0..3
    float accx = 0.f, accy = 0.f;
    for (int s = q; s < SS_; s += 4) {
      f32x2 ft = *(const f32x2*)(inarr + ((size_t)rowoff[s] << 8) + c2);
      float w = sm[s];
      accx = fmaf(w, ft[0], accx);
      accy = fmaf(w, ft[1], accy);
    }
    __syncthreads();
    ldsf[q * 256 + c2]     = accx;
    ldsf[q * 256 + c2 + 1] = accy;
    __syncthreads();
    if (tid < 256) {
      float tot = ldsf[tid] + ldsf[256 + tid] + ldsf[512 + tid] + ldsf[768 + tid];
      if (!is_t) out[2048 + ((size_t)(b * 256 + tid) * 17 + u) * 17 + v] = tot;
      else       out[b * 256 + tid] = tot;
    }
  }
}

// ---------------------------------------------------------------------------
extern "C" void kernel_launch(void* const* d_in, const int* in_sizes, int n_in,
                              void* d_out, int out_size, void* d_ws, size_t ws_size,
                              hipStream_t stream)
{
  const float* templ = (const float*)d_in[0];
  const float* cand  = (const float*)d_in[1];
  const float* w0 = (const float*)d_in[2];
  const float* w1 = (const float*)d_in[3];
  const float* w2 = (const float*)d_in[4];
  const float* w3 = (const float*)d_in[5];
  const float* w4 = (const float*)d_in[6];
  const float* w5 = (const float*)d_in[7];
  const float* w6 = (const float*)d_in[8];

  float* ws    = (float*)d_ws;
  float* inarr = ws + OFF_IN;
  float* out0  = ws + OFF_OUT0;
  float* rows  = ws + OFF_ROWS;
  float* m0v   = ws + OFF_M0;
  float* tm0v  = ws + OFF_TM0;
  half_t* w0h  = (half_t*)(ws + OFF_F16);
  half_t* w1h  = w0h + NW0H;
  half_t* w2h  = w1h + 128 * 256;
  half_t* w3h  = w2h + 64 * 128;
  float* outf  = (float*)d_out;

  prep_kernel<<<2048, 256, 0, stream>>>(templ, cand, w0, w1, w2, w3,
                                        inarr, w0h, w1h, w2h, w3h);
  l0gemm_kernel<<<NROW / 16, 512, 0, stream>>>(inarr, w0h, out0);
  rowsum_kernel<<<B_ * 31 * 17, 256, 0, stream>>>(out0, rows);
  colsum_kernel<<<B_ * KK_, 256, 0, stream>>>(rows, m0v);
  tmean0_kernel<<<B_, 256, 0, stream>>>(out0, tm0v);
  chain_kernel<<<B_ * KK_ + B_, 512, 0, stream>>>(out0, m0v, tm0v,
                                                  w1h, w2h, w3h, w4, w5, w6,
                                                  inarr, outf);
}

// Round 16
// 276.991 us; speedup vs baseline: 1.7996x; 1.0910x over previous
//
#include <hip/hip_runtime.h>

typedef _Float16 half_t;
typedef half_t half4 __attribute__((ext_vector_type(4)));
typedef half_t half8 __attribute__((ext_vector_type(8)));
typedef __fp16 pk16x2 __attribute__((ext_vector_type(2)));
typedef float  f32x4 __attribute__((ext_vector_type(4)));
typedef float  f32x2 __attribute__((ext_vector_type(2)));

static __device__ __forceinline__ half4 pack4(f32x4 a) {
  pk16x2 lo = __builtin_amdgcn_cvt_pkrtz(a[0], a[1]);
  pk16x2 hi = __builtin_amdgcn_cvt_pkrtz(a[2], a[3]);
  half4 h;
  h[0] = lo[0]; h[1] = lo[1]; h[2] = hi[0]; h[3] = hi[1];
  return h;
}

constexpr int B_  = 8;
constexpr int S_  = 15;
constexpr int K_  = 17;
constexpr int P_  = 31;
constexpr int SS_ = 225;
constexpr int PP_ = 961;
constexpr int KK_ = 289;

constexpr int NROW_C = B_ * PP_;          // 7688
constexpr int NROW_T = B_ * SS_;          // 1800
constexpr int NROW   = NROW_C + NROW_T;   // 9488 = 593*16

constexpr int NW0H = 512 * 256;                   // w0h f16 (conv1 rows | g rows)
constexpr int NF16 = 128*256 + 64*128 + 32*64;    // w1h | w2h | w3h

// workspace float offsets
constexpr size_t OFF_IN   = 0;
constexpr size_t OFF_OUT0 = OFF_IN   + (size_t)NROW * 256;
constexpr size_t OFF_ROWS = OFF_OUT0 + (size_t)NROW * 512;
constexpr size_t OFF_M0   = OFF_ROWS + (size_t)B_ * 31 * 17 * 256;
constexpr size_t OFF_TM0  = OFF_M0   + (size_t)B_ * KK_ * 256;
constexpr size_t OFF_F16  = OFF_TM0  + (size_t)B_ * 256;   // f16 arena

// chain LDS byte offsets
// transient: X0B 0..32768 (x0 full-K [64][512B] swz; x2 [64][128B] aliases; final reduce)
//            X1B 32768..49152 (x1 [64][256B] swz; x3T + y4T alias after L2)
constexpr int X0B  = 0;
constexpr int X1B  = 32768;
constexpr int X3TB = 32768;   // f32 x3T [64][36f] (alias dead x1)
constexpr int Y4B  = 41984;   // f32 y4T [64][20f] (alias dead x1)
// persistent (must NOT overlap x1's 32768..49152 span):
constexpr int SMB  = 49152;   // 240 f logits
constexpr int REDB = 50112;   // 16 f
constexpr int W4B  = 50176;   // w4 [16][36f] (2304 B)
constexpr int W5B  = 52480;   // w5 [8][20f]  (640 B)
constexpr int W6B  = 53120;   // w6 [8] (32 B)
constexpr int ROWB = 53152;   // 225 u16 row table
constexpr int LDSB = 53632;   // x3 = 160896 <= 163840 -> 3 blocks/CU

// ---------------------------------------------------------------------------
// coalesced channel-last transpose: LDS tile [32 pos][257f]
// ---------------------------------------------------------------------------
__global__ __launch_bounds__(256) void featT_kernel(
    const float* __restrict__ templ, const float* __restrict__ cand,
    float* __restrict__ inarr)
{
  __shared__ float tile[32 * 257];
  const int bid = blockIdx.x;
  const float* src;
  int base, npos, rowbase;
  if (bid < B_ * 31) {                 // cand: 31 chunks of 32 (30*32+1 = 961)
    int b = bid / 31, ch = bid % 31;
    src = cand + (size_t)b * 256 * PP_;
    base = ch * 32; npos = min(32, PP_ - base);
    rowbase = b * PP_ + base;
  } else {                             // templ: 8 chunks of 32 (7*32+1 = 225)
    int t = bid - B_ * 31;
    int b = t / 8, ch = t % 8;
    src = templ + (size_t)b * 256 * SS_;
    base = ch * 32; npos = min(32, SS_ - base);
    rowbase = NROW_C + b * SS_ + base;
  }
  const int tid = threadIdx.x;
  const int p  = tid & 31;             // pos within chunk (coalesced read dim)
  const int c8 = tid >> 5;             // 8 channel groups
  const int stride = (bid < B_ * 31) ? PP_ : SS_;
  if (p < npos) {
    for (int it = 0; it < 32; ++it) {
      int c = c8 * 32 + it;
      tile[p * 257 + c] = src[(size_t)c * stride + base + p];
    }
  }
  __syncthreads();
  for (int pp = 0; pp < npos; ++pp)
    inarr[(size_t)(rowbase + pp) * 256 + tid] = tile[pp * 257 + tid];
}

// ---------------------------------------------------------------------------
__global__ __launch_bounds__(256) void wcvt_kernel(
    const float* __restrict__ w0, const float* __restrict__ w1,
    const float* __restrict__ w2, const float* __restrict__ w3,
    half_t* __restrict__ w0h, half_t* __restrict__ w1h,
    half_t* __restrict__ w2h, half_t* __restrict__ w3h)
{
  const int total = NW0H + NF16;
  for (int idx = blockIdx.x * blockDim.x + threadIdx.x; idx < total;
       idx += gridDim.x * blockDim.x) {
    if (idx < NW0H) {
      int m = idx >> 8; int c = idx & 255;
      // rows 0..255 = conv1 weights (w0[:,256:]); rows 256..511 = g weights
      w0h[idx] = (half_t)(m < 256 ? w0[m * 512 + 256 + c] : w0[(m - 256) * 512 + c]);
    } else {
      int t = idx - NW0H;
      if (t < 32768)      w1h[t] = (half_t)w1[t];                  // [128][256]
      else if (t < 40960) w2h[t - 32768] = (half_t)w2[t - 32768];  // [64][128]
      else                w3h[t - 40960] = (half_t)w3[t - 40960];  // [32][64]
    }
  }
}

// ---------------------------------------------------------------------------
// layer-0 GEMM via MFMA: out0[row][m] = sum_c w0h[m][c] * in[row][c], m<512
// ---------------------------------------------------------------------------
__global__ __launch_bounds__(512) void l0gemm_kernel(
    const float* __restrict__ in, const half_t* __restrict__ w0h,
    float* __restrict__ out0)
{
  __shared__ __align__(16) char xls[16 * 512];   // [16 rows][256ch] f16 swz
  const int tid  = threadIdx.x;
  const int lane = tid & 63;
  const int wvs  = tid >> 6;
  const int row0 = blockIdx.x * 16;

  {
    const int row = tid >> 5;
    const int c8  = (tid & 31) * 8;
    const float* src = in + (size_t)(row0 + row) * 256 + c8;
    half8 h;
#pragma unroll
    for (int r = 0; r < 8; ++r) h[r] = (half_t)src[r];
    const int off = (row * 512 + c8 * 2) ^ ((row & 7) << 4);
    *(half8*)(xls + off) = h;
  }
  __syncthreads();

  const int l15 = lane & 15, g = lane >> 4;
  f32x4 acc[4];
#pragma unroll
  for (int mt = 0; mt < 4; ++mt) acc[mt] = (f32x4){0.f, 0.f, 0.f, 0.f};
#pragma unroll 2
  for (int kb = 0; kb < 8; ++kb) {
    const int off = (l15 * 512 + kb * 64 + g * 16) ^ ((l15 & 7) << 4);
    half8 bfr = *(const half8*)(xls + off);
#pragma unroll
    for (int mt = 0; mt < 4; ++mt) {
      const half_t* ap = w0h + (size_t)((wvs * 4 + mt) * 16 + l15) * 256 + kb * 32 + g * 8;
      half8 a = *(const half8*)ap;
      acc[mt] = __builtin_amdgcn_mfma_f32_16x16x32_f16(a, bfr, acc[mt], 0, 0, 0);
    }
  }
#pragma unroll
  for (int mt = 0; mt < 4; ++mt) {
    const int m0c = (wvs * 4 + mt) * 16 + g * 4;
    *(f32x4*)(out0 + (size_t)(row0 + l15) * 512 + m0c) = acc[mt];
  }
}

// ---------------------------------------------------------------------------
__global__ __launch_bounds__(256) void rowsum_kernel(
    const float* __restrict__ out0, float* __restrict__ rows)
{
  const int bid = blockIdx.x;
  const int o = threadIdx.x;
  const int v = bid % 17; const int p = (bid / 17) % 31; const int b = bid / (17 * 31);
  float s = 0.f;
  for (int j = 0; j < 15; ++j)
    s += out0[(size_t)(b * PP_ + p * P_ + v + j) * 512 + 256 + o];
  rows[(size_t)bid * 256 + o] = s;
}

__global__ __launch_bounds__(256) void colsum_kernel(
    const float* __restrict__ rows, float* __restrict__ m0v)
{
  const int bid = blockIdx.x;
  const int o = threadIdx.x;
  const int v = bid % 17; const int u = (bid / 17) % 17; const int b = bid / KK_;
  float s = 0.f;
  for (int i = 0; i < 15; ++i)
    s += rows[(size_t)((b * 31 + u + i) * 17 + v) * 256 + o];
  m0v[(size_t)bid * 256 + o] = s * (1.0f / 225.0f);
}

__global__ __launch_bounds__(256) void tmean0_kernel(
    const float* __restrict__ out0, float* __restrict__ tm0v)
{
  const int b = blockIdx.x;
  const int o = threadIdx.x;
  float s = 0.f;
  for (int t = 0; t < SS_; ++t)
    s += out0[(size_t)(NROW_C + b * SS_ + t) * 512 + 256 + o];
  tm0v[b * 256 + o] = s * (1.0f / 225.0f);
}

// ---------------------------------------------------------------------------
__global__ __launch_bounds__(512, 4) void chain_kernel(
    const float* __restrict__ out0, const float* __restrict__ m0v,
    const float* __restrict__ tm0v,
    const half_t* __restrict__ w1h, const half_t* __restrict__ w2h,
    const half_t* __restrict__ w3h,
    const float* __restrict__ w4, const float* __restrict__ w5,
    const float* __restrict__ w6,
    const float* __restrict__ inarr, float* __restrict__ out)
{
  __shared__ __align__(16) char lds[LDSB];
  float*    ldsf   = (float*)lds;
  float*    sm     = (float*)(lds + SMB);
  float*    red    = (float*)(lds + REDB);
  uint16_t* rowoff = (uint16_t*)(lds + ROWB);

  const int tid  = threadIdx.x;
  const int lane = tid & 63;
  const int wvs  = __builtin_amdgcn_readfirstlane(tid >> 6);
  const int bid  = (blockIdx.x & 7) * 290 + (blockIdx.x >> 3);   // XCD swizzle (2320 = 8*290)
  const bool is_t = (bid >= B_ * KK_);
  int b, u = 0, v = 0;
  const float* mean_vec;
  if (!is_t) {
    b = bid / KK_;
    int r = bid % KK_;
    u = r / K_; v = r % K_;
    mean_vec = m0v + (size_t)bid * 256;
  } else {
    b = bid - B_ * KK_;
    mean_vec = tm0v + (size_t)b * 256;
  }

  // one-time LDS staging: row table + small weights (persistent region)
  if (tid < SS_) {
    int i = tid / 15, j = tid - i * 15;
    rowoff[tid] = is_t ? (uint16_t)(NROW_C + b * SS_ + tid)
                       : (uint16_t)(b * PP_ + (u + i) * P_ + (v + j));
  }
  ((float*)(lds + W4B))[(tid >> 5) * 36 + (tid & 31)] = w4[tid];       // [16][36f]
  if (tid < 128) ((float*)(lds + W5B))[(tid >> 4) * 20 + (tid & 15)] = w5[tid]; // [8][20f]
  if (tid < 8)   ((float*)(lds + W6B))[tid] = w6[tid];

  // W1 fragment base (streamed per tile — not hoisted)
  const half_t* w1base = w1h + (size_t)(16 * wvs + (lane & 15)) * 256 + ((lane >> 4) << 3);
  const int g2 = wvs & 3, h2 = wvs >> 2;
  half8 af2[4];
  {
    const half_t* base = w2h + (size_t)(16 * g2 + (lane & 15)) * 128 + ((lane >> 4) << 3);
#pragma unroll
    for (int kb = 0; kb < 4; ++kb) af2[kb] = *(const half8*)(base + kb * 32);
  }
  const int rt3 = wvs & 1, ct3 = wvs >> 1;
  const half_t* b3ptr = w3h + (size_t)(16 * rt3 + (lane & 15)) * 64 + ((lane >> 4) << 3);
  // staging: lane covers 8 channels of 2 positions (b128 writes, conflict-free)
  const int c8  = (lane & 31) * 8;
  const int lhi = lane >> 5;
  const f32x4 mv8a = *(const f32x4*)(mean_vec + c8);
  const f32x4 mv8b = *(const f32x4*)(mean_vec + c8 + 4);
  __syncthreads();   // rowoff/table visibility before staging reads it

  for (int ti = 0; ti < 4; ++ti) {
    const int s0 = ti * 64;
    const int cnt = min(64, SS_ - s0);

    // ---- stage x0 full-K: [pos][256ch] f16 swz, 8 pos/wave, b128 writes
    for (int it = 0; it < 4; ++it) {
      const int pos = 8 * wvs + it * 2 + lhi;
      const int srow = rowoff[min(s0 + pos, SS_ - 1)];
      f32x4 xa = *(const f32x4*)(out0 + ((size_t)srow << 9) + c8);
      f32x4 xb = *(const f32x4*)(out0 + ((size_t)srow << 9) + c8 + 4);
      f32x4 a0, a1;
#pragma unroll
      for (int r = 0; r < 4; ++r) {
        float t2 = xa[r] + mv8a[r];
        a0[r] = fmaxf(t2, 0.01f * t2);
        float t3 = xb[r] + mv8b[r];
        a1[r] = fmaxf(t3, 0.01f * t3);
      }
      half4 h0 = pack4(a0), h1 = pack4(a1);
      half8 h8;
#pragma unroll
      for (int r = 0; r < 4; ++r) { h8[r] = h0[r]; h8[4 + r] = h1[r]; }
      const int off = (pos * 512 + c8 * 2) ^ ((pos & 7) << 4);
      *(half8*)(lds + X0B + off) = h8;
    }
    __syncthreads();

    // ---- layer 1: 256 -> 128 MFMA (full K), W1 streamed
    f32x4 acc[4];
#pragma unroll
    for (int nt = 0; nt < 4; ++nt) acc[nt] = (f32x4){0.f, 0.f, 0.f, 0.f};
    {
      const half_t* w1p = w1base;
      asm volatile("" : "+v"(w1p));   // defeat hoisting across tiles
#pragma unroll 2
      for (int kb = 0; kb < 8; ++kb) {
        half8 a1 = *(const half8*)(w1p + kb * 32);
        const int kbyte = kb * 64 + ((lane >> 4) << 4);
#pragma unroll
        for (int nt = 0; nt < 4; ++nt) {
          const int pos = nt * 16 + (lane & 15);
          const int off = (pos * 512 + kbyte) ^ ((pos & 7) << 4);
          half8 bfr = *(const half8*)(lds + X0B + off);
          acc[nt] = __builtin_amdgcn_mfma_f32_16x16x32_f16(a1, bfr, acc[nt], 0, 0, 0);
        }
      }
#pragma unroll
      for (int nt = 0; nt < 4; ++nt) {
        const int pos = nt * 16 + (lane & 15);
        f32x4 a;
#pragma unroll
        for (int r = 0; r < 4; ++r) a[r] = fmaxf(acc[nt][r], 0.01f * acc[nt][r]);
        const int ch0 = 16 * wvs + ((lane >> 4) << 2);
        const int off = (pos * 256 + ch0 * 2) ^ ((pos & 7) << 4);
        *(half4*)(lds + X1B + off) = pack4(a);
      }
    }
    __syncthreads();

    // ---- layer 2: 128 -> 64 MFMA; epilogue -> x2 f16 [pos][64ch] swz (X0 region)
    f32x4 acc2[2];
#pragma unroll
    for (int nt = 0; nt < 2; ++nt) acc2[nt] = (f32x4){0.f, 0.f, 0.f, 0.f};
#pragma unroll
    for (int kb = 0; kb < 4; ++kb) {
      const int kbyte = kb * 64 + ((lane >> 4) << 4);
#pragma unroll
      for (int nt = 0; nt < 2; ++nt) {
        const int pos = h2 * 32 + nt * 16 + (lane & 15);
        const int off = (pos * 256 + kbyte) ^ ((pos & 7) << 4);
        half8 bfr = *(const half8*)(lds + X1B + off);
        acc2[nt] = __builtin_amdgcn_mfma_f32_16x16x32_f16(af2[kb], bfr, acc2[nt], 0, 0, 0);
      }
    }
#pragma unroll
    for (int nt = 0; nt < 2; ++nt) {
      const int pos = h2 * 32 + nt * 16 + (lane & 15);
      const int ch0 = 16 * g2 + ((lane >> 4) << 2);
      f32x4 a;
#pragma unroll
      for (int r = 0; r < 4; ++r) a[r] = fmaxf(acc2[nt][r], 0.01f * acc2[nt][r]);
      const int off = (pos * 128 + ch0 * 2) ^ ((pos & 7) << 4);
      *(half4*)(lds + X0B + off) = pack4(a);
    }
    __syncthreads();

    // ---- layer 3: 64 -> 32 MFMA; epilogue -> x3T f32 [pos][36f] (alias dead x1)
    {
      f32x4 acc3 = (f32x4){0.f, 0.f, 0.f, 0.f};
      const int pos = ct3 * 16 + (lane & 15);
#pragma unroll
      for (int kb = 0; kb < 2; ++kb) {
        half8 a3 = *(const half8*)(b3ptr + kb * 32);
        const int kbyte = kb * 64 + ((lane >> 4) << 4);
        const int off = (pos * 128 + kbyte) ^ ((pos & 7) << 4);
        half8 bfr = *(const half8*)(lds + X0B + off);
        acc3 = __builtin_amdgcn_mfma_f32_16x16x32_f16(a3, bfr, acc3, 0, 0, 0);
      }
      const int ch0 = 16 * rt3 + ((lane >> 4) << 2);
      f32x4 o4;
#pragma unroll
      for (int r = 0; r < 4; ++r) o4[r] = fmaxf(acc3[r], 0.01f * acc3[r]);
      *(f32x4*)(lds + X3TB + pos * 144 + ch0 * 4) = o4;
    }
    __syncthreads();

    // ---- layers 4-6, pos-sliced per wave (pos 8*wvs..+7), barrier-free
    {
      const int p = lane >> 3, g = lane & 7;
      const int pos = 8 * wvs + p;
      float a4_0 = 0.f, a4_1 = 0.f;
#pragma unroll
      for (int c0 = 0; c0 < 32; c0 += 4) {
        f32x4 x  = *(const f32x4*)(lds + X3TB + pos * 144 + c0 * 4);
        f32x4 wA = *(const f32x4*)(lds + W4B + (2 * g) * 144 + c0 * 4);
        f32x4 wB = *(const f32x4*)(lds + W4B + (2 * g + 1) * 144 + c0 * 4);
#pragma unroll
        for (int r = 0; r < 4; ++r) {
          a4_0 = fmaf(wA[r], x[r], a4_0);
          a4_1 = fmaf(wB[r], x[r], a4_1);
        }
      }
      f32x2 y4v;
      y4v[0] = fmaxf(a4_0, 0.01f * a4_0);
      y4v[1] = fmaxf(a4_1, 0.01f * a4_1);
      *(f32x2*)(lds + Y4B + pos * 80 + g * 8) = y4v;
      float a5 = 0.f;
#pragma unroll
      for (int c0 = 0; c0 < 16; c0 += 4) {
        f32x4 x = *(const f32x4*)(lds + Y4B + pos * 80 + c0 * 4);
        f32x4 w = *(const f32x4*)(lds + W5B + g * 80 + c0 * 4);
#pragma unroll
        for (int r = 0; r < 4; ++r) a5 = fmaf(w[r], x[r], a5);
      }
      a5 = fmaxf(a5, 0.01f * a5);
      float t6 = ((float*)(lds + W6B))[g] * a5;
      t6 += __shfl_xor(t6, 1);
      t6 += __shfl_xor(t6, 2);
      t6 += __shfl_xor(t6, 4);
      if (g == 0 && (8 * wvs + p) < cnt) sm[s0 + pos] = t6;
    }
    __syncthreads();
  }

  // ---- softmax over 225 logits
  float vv = (tid < SS_) ? sm[tid] : -1e30f;
  float m = vv;
#pragma unroll
  for (int off = 32; off >= 1; off >>= 1) m = fmaxf(m, __shfl_xor(m, off));
  if (lane == 0) red[wvs] = m;
  __syncthreads();
  m = red[0];
#pragma unroll
  for (int w = 1; w < 8; ++w) m = fmaxf(m, red[w]);
  float e = (tid < SS_) ? __expf(vv - m) : 0.f;
  float ss = e;
#pragma unroll
  for (int off = 32; off >= 1; off >>= 1) ss += __shfl_xor(ss, off);
  __syncthreads();
  if (lane == 0) red[wvs] = ss;
  __syncthreads();
  float Stot = red[0];
#pragma unroll
  for (int w = 1; w < 8; ++w) Stot += red[w];
  if (tid < SS_) sm[tid] = e / Stot;
  __syncthreads();

  // ---- weighted channel sum: 2 channels/thread, 4-way position split
  {
    const int c2 = (tid & 127) * 2;
    const int q  = tid >> 7;          // 0..3
    float accx = 0.f, accy = 0.f;
    for (int s = q; s < SS_; s += 4) {
      f32x2 ft = *(const f32x2*)(inarr + ((size_t)rowoff[s] << 8) + c2);
      float w = sm[s];
      accx = fmaf(w, ft[0], accx);
      accy = fmaf(w, ft[1], accy);
    }
    __syncthreads();
    ldsf[q * 256 + c2]     = accx;
    ldsf[q * 256 + c2 + 1] = accy;
    __syncthreads();
    if (tid < 256) {
      float tot = ldsf[tid] + ldsf[256 + tid] + ldsf[512 + tid] + ldsf[768 + tid];
      if (!is_t) out[2048 + ((size_t)(b * 256 + tid) * 17 + u) * 17 + v] = tot;
      else       out[b * 256 + tid] = tot;
    }
  }
}

// ---------------------------------------------------------------------------
extern "C" void kernel_launch(void* const* d_in, const int* in_sizes, int n_in,
                              void* d_out, int out_size, void* d_ws, size_t ws_size,
                              hipStream_t stream)
{
  const float* templ = (const float*)d_in[0];
  const float* cand  = (const float*)d_in[1];
  const float* w0 = (const float*)d_in[2];
  const float* w1 = (const float*)d_in[3];
  const float* w2 = (const float*)d_in[4];
  const float* w3 = (const float*)d_in[5];
  const float* w4 = (const float*)d_in[6];
  const float* w5 = (const float*)d_in[7];
  const float* w6 = (const float*)d_in[8];

  float* ws    = (float*)d_ws;
  float* inarr = ws + OFF_IN;
  float* out0  = ws + OFF_OUT0;
  float* rows  = ws + OFF_ROWS;
  float* m0v   = ws + OFF_M0;
  float* tm0v  = ws + OFF_TM0;
  half_t* w0h  = (half_t*)(ws + OFF_F16);
  half_t* w1h  = w0h + NW0H;
  half_t* w2h  = w1h + 128 * 256;
  half_t* w3h  = w2h + 64 * 128;
  float* outf  = (float*)d_out;

  featT_kernel<<<B_ * 31 + B_ * 8, 256, 0, stream>>>(templ, cand, inarr);
  wcvt_kernel<<<256, 256, 0, stream>>>(w0, w1, w2, w3, w0h, w1h, w2h, w3h);
  l0gemm_kernel<<<NROW / 16, 512, 0, stream>>>(inarr, w0h, out0);
  rowsum_kernel<<<B_ * 31 * 17, 256, 0, stream>>>(out0, rows);
  colsum_kernel<<<B_ * KK_, 256, 0, stream>>>(rows, m0v);
  tmean0_kernel<<<B_, 256, 0, stream>>>(out0, tm0v);
  chain_kernel<<<B_ * KK_ + B_, 512, 0, stream>>>(out0, m0v, tm0v,
                                                  w1h, w2h, w3h, w4, w5, w6,
                                                  inarr, outf);
}

// Round 17
// 269.041 us; speedup vs baseline: 1.8528x; 1.0295x over previous
//
#include <hip/hip_runtime.h>

typedef _Float16 half_t;
typedef half_t h2    __attribute__((ext_vector_type(2)));
typedef half_t half4 __attribute__((ext_vector_type(4)));
typedef half_t half8 __attribute__((ext_vector_type(8)));
typedef __fp16 pk16x2 __attribute__((ext_vector_type(2)));
typedef float  f32x4 __attribute__((ext_vector_type(4)));
typedef float  f32x2 __attribute__((ext_vector_type(2)));

static __device__ __forceinline__ half4 pack4(f32x4 a) {
  pk16x2 lo = __builtin_amdgcn_cvt_pkrtz(a[0], a[1]);
  pk16x2 hi = __builtin_amdgcn_cvt_pkrtz(a[2], a[3]);
  half4 h;
  h[0] = lo[0]; h[1] = lo[1]; h[2] = hi[0]; h[3] = hi[1];
  return h;
}

constexpr int B_  = 8;
constexpr int S_  = 15;
constexpr int K_  = 17;
constexpr int P_  = 31;
constexpr int SS_ = 225;
constexpr int PP_ = 961;
constexpr int KK_ = 289;

constexpr int NROW_C = B_ * PP_;          // 7688
constexpr int NROW_T = B_ * SS_;          // 1800
constexpr int NROW   = NROW_C + NROW_T;   // 9488 = 593*16

constexpr int NW0H = 512 * 256;                   // w0h f16 (conv1 rows | g rows)
constexpr int NF16 = 128*256 + 64*128 + 32*64;    // w1h | w2h | w3h

// workspace float offsets
constexpr size_t OFF_GOUT = 0;                               // [NROW][256] f32 g
constexpr size_t OFF_ROWS = OFF_GOUT + (size_t)NROW * 256;
constexpr size_t OFF_M0   = OFF_ROWS + (size_t)B_ * 31 * 17 * 256;
constexpr size_t OFF_TM0  = OFF_M0   + (size_t)B_ * KK_ * 256;
constexpr size_t OFF_F16  = OFF_TM0  + (size_t)B_ * 256;     // f16 arena start

// chain LDS byte offsets (53,632 B -> 3 blocks/CU)
constexpr int X0B  = 0;       // f16 x0 [64][512B] swz (x2 aliases; final reduce)
constexpr int X1B  = 32768;   // f16 x1 [64][256B] swz
constexpr int X3TB = 32768;   // f32 x3T [64][36f] (alias dead x1)
constexpr int Y4B  = 41984;   // f32 y4T [64][20f] (alias dead x1)
constexpr int SMB  = 49152;   // 240 f logits (then packed h2 weights)
constexpr int REDB = 50112;   // 16 f
constexpr int W4B  = 50176;   // w4 [16][36f]
constexpr int W5B  = 52480;   // w5 [8][20f]
constexpr int W6B  = 53120;   // w6 [8]
constexpr int ROWB = 53152;   // 225 u16 row table
constexpr int LDSB = 53632;

// ---------------------------------------------------------------------------
// coalesced channel-last transpose -> f16 features
// ---------------------------------------------------------------------------
__global__ __launch_bounds__(256) void featT_kernel(
    const float* __restrict__ templ, const float* __restrict__ cand,
    half_t* __restrict__ inarrh)
{
  __shared__ float tile[32 * 257];
  const int bid = blockIdx.x;
  const float* src;
  int base, npos, rowbase;
  if (bid < B_ * 31) {
    int b = bid / 31, ch = bid % 31;
    src = cand + (size_t)b * 256 * PP_;
    base = ch * 32; npos = min(32, PP_ - base);
    rowbase = b * PP_ + base;
  } else {
    int t = bid - B_ * 31;
    int b = t / 8, ch = t % 8;
    src = templ + (size_t)b * 256 * SS_;
    base = ch * 32; npos = min(32, SS_ - base);
    rowbase = NROW_C + b * SS_ + base;
  }
  const int tid = threadIdx.x;
  const int p  = tid & 31;
  const int c8 = tid >> 5;
  const int stride = (bid < B_ * 31) ? PP_ : SS_;
  if (p < npos) {
    for (int it = 0; it < 32; ++it) {
      int c = c8 * 32 + it;
      tile[p * 257 + c] = src[(size_t)c * stride + base + p];
    }
  }
  __syncthreads();
  for (int pp = 0; pp < npos; ++pp)
    inarrh[(size_t)(rowbase + pp) * 256 + tid] = (half_t)tile[pp * 257 + tid];
}

// ---------------------------------------------------------------------------
__global__ __launch_bounds__(256) void wcvt_kernel(
    const float* __restrict__ w0, const float* __restrict__ w1,
    const float* __restrict__ w2, const float* __restrict__ w3,
    half_t* __restrict__ w0h, half_t* __restrict__ w1h,
    half_t* __restrict__ w2h, half_t* __restrict__ w3h)
{
  const int total = NW0H + NF16;
  for (int idx = blockIdx.x * blockDim.x + threadIdx.x; idx < total;
       idx += gridDim.x * blockDim.x) {
    if (idx < NW0H) {
      int m = idx >> 8; int c = idx & 255;
      w0h[idx] = (half_t)(m < 256 ? w0[m * 512 + 256 + c] : w0[(m - 256) * 512 + c]);
    } else {
      int t = idx - NW0H;
      if (t < 32768)      w1h[t] = (half_t)w1[t];
      else if (t < 40960) w2h[t - 32768] = (half_t)w2[t - 32768];
      else                w3h[t - 40960] = (half_t)w3[t - 40960];
    }
  }
}

// ---------------------------------------------------------------------------
// layer-0 GEMM via MFMA; conv1 -> f16 conv1h, g -> f32 gout
// ---------------------------------------------------------------------------
__global__ __launch_bounds__(512) void l0gemm_kernel(
    const half_t* __restrict__ inh, const half_t* __restrict__ w0h,
    half_t* __restrict__ conv1h, float* __restrict__ gout)
{
  __shared__ __align__(16) char xls[16 * 512];   // [16 rows][256ch] f16 swz
  const int tid  = threadIdx.x;
  const int lane = tid & 63;
  const int wvs  = tid >> 6;
  const int row0 = blockIdx.x * 16;

  {
    const int row = tid >> 5;
    const int c8  = (tid & 31) * 8;
    half8 h = *(const half8*)(inh + (size_t)(row0 + row) * 256 + c8);
    const int off = (row * 512 + c8 * 2) ^ ((row & 7) << 4);
    *(half8*)(xls + off) = h;
  }
  __syncthreads();

  const int l15 = lane & 15, g = lane >> 4;
  f32x4 acc[4];
#pragma unroll
  for (int mt = 0; mt < 4; ++mt) acc[mt] = (f32x4){0.f, 0.f, 0.f, 0.f};
#pragma unroll 2
  for (int kb = 0; kb < 8; ++kb) {
    const int off = (l15 * 512 + kb * 64 + g * 16) ^ ((l15 & 7) << 4);
    half8 bfr = *(const half8*)(xls + off);
#pragma unroll
    for (int mt = 0; mt < 4; ++mt) {
      const half_t* ap = w0h + (size_t)((wvs * 4 + mt) * 16 + l15) * 256 + kb * 32 + g * 8;
      half8 a = *(const half8*)ap;
      acc[mt] = __builtin_amdgcn_mfma_f32_16x16x32_f16(a, bfr, acc[mt], 0, 0, 0);
    }
  }
#pragma unroll
  for (int mt = 0; mt < 4; ++mt) {
    const int m0c = (wvs * 4 + mt) * 16 + g * 4;
    if (wvs < 4)
      *(half4*)(conv1h + (size_t)(row0 + l15) * 256 + m0c) = pack4(acc[mt]);
    else
      *(f32x4*)(gout + (size_t)(row0 + l15) * 256 + (m0c - 256)) = acc[mt];
  }
}

// ---------------------------------------------------------------------------
__global__ __launch_bounds__(256) void rowsum_kernel(
    const float* __restrict__ gout, float* __restrict__ rows)
{
  const int bid = blockIdx.x;
  const int o = threadIdx.x;
  const int v = bid % 17; const int p = (bid / 17) % 31; const int b = bid / (17 * 31);
  float s = 0.f;
  for (int j = 0; j < 15; ++j)
    s += gout[(size_t)(b * PP_ + p * P_ + v + j) * 256 + o];
  rows[(size_t)bid * 256 + o] = s;
}

__global__ __launch_bounds__(256) void colsum_kernel(
    const float* __restrict__ rows, float* __restrict__ m0v)
{
  const int bid = blockIdx.x;
  const int o = threadIdx.x;
  const int v = bid % 17; const int u = (bid / 17) % 17; const int b = bid / KK_;
  float s = 0.f;
  for (int i = 0; i < 15; ++i)
    s += rows[(size_t)((b * 31 + u + i) * 17 + v) * 256 + o];
  m0v[(size_t)bid * 256 + o] = s * (1.0f / 225.0f);
}

__global__ __launch_bounds__(256) void tmean0_kernel(
    const float* __restrict__ gout, float* __restrict__ tm0v)
{
  const int b = blockIdx.x;
  const int o = threadIdx.x;
  float s = 0.f;
  for (int t = 0; t < SS_; ++t)
    s += gout[(size_t)(NROW_C + b * SS_ + t) * 256 + o];
  tm0v[b * 256 + o] = s * (1.0f / 225.0f);
}

// ---------------------------------------------------------------------------
__global__ __launch_bounds__(512, 4) void chain_kernel(
    const half_t* __restrict__ conv1h, const float* __restrict__ m0v,
    const float* __restrict__ tm0v,
    const half_t* __restrict__ w1h, const half_t* __restrict__ w2h,
    const half_t* __restrict__ w3h,
    const float* __restrict__ w4, const float* __restrict__ w5,
    const float* __restrict__ w6,
    const half_t* __restrict__ inarrh, float* __restrict__ out)
{
  __shared__ __align__(16) char lds[LDSB];
  float*    ldsf   = (float*)lds;
  float*    sm     = (float*)(lds + SMB);
  float*    red    = (float*)(lds + REDB);
  uint16_t* rowoff = (uint16_t*)(lds + ROWB);

  const int tid  = threadIdx.x;
  const int lane = tid & 63;
  const int wvs  = __builtin_amdgcn_readfirstlane(tid >> 6);
  const int bid  = (blockIdx.x & 7) * 290 + (blockIdx.x >> 3);   // XCD swizzle (2320 = 8*290)
  const bool is_t = (bid >= B_ * KK_);
  int b, u = 0, v = 0;
  const float* mean_vec;
  if (!is_t) {
    b = bid / KK_;
    int r = bid % KK_;
    u = r / K_; v = r % K_;
    mean_vec = m0v + (size_t)bid * 256;
  } else {
    b = bid - B_ * KK_;
    mean_vec = tm0v + (size_t)b * 256;
  }

  // one-time LDS staging: row table + small weights (persistent region)
  if (tid < SS_) {
    int i = tid / 15, j = tid - i * 15;
    rowoff[tid] = is_t ? (uint16_t)(NROW_C + b * SS_ + tid)
                       : (uint16_t)(b * PP_ + (u + i) * P_ + (v + j));
  }
  ((float*)(lds + W4B))[(tid >> 5) * 36 + (tid & 31)] = w4[tid];       // [16][36f]
  if (tid < 128) ((float*)(lds + W5B))[(tid >> 4) * 20 + (tid & 15)] = w5[tid]; // [8][20f]
  if (tid < 8)   ((float*)(lds + W6B))[tid] = w6[tid];

  // W1 fragment base (streamed per tile — not hoisted)
  const half_t* w1base = w1h + (size_t)(16 * wvs + (lane & 15)) * 256 + ((lane >> 4) << 3);
  const int g2 = wvs & 3, h2w = wvs >> 2;
  half8 af2[4];
  {
    const half_t* base = w2h + (size_t)(16 * g2 + (lane & 15)) * 128 + ((lane >> 4) << 3);
#pragma unroll
    for (int kb = 0; kb < 4; ++kb) af2[kb] = *(const half8*)(base + kb * 32);
  }
  const int rt3 = wvs & 1, ct3 = wvs >> 1;
  const half_t* b3ptr = w3h + (size_t)(16 * rt3 + (lane & 15)) * 64 + ((lane >> 4) << 3);
  // staging: lane covers 8 channels of 2 positions (b128 ops)
  const int c8  = (lane & 31) * 8;
  const int lhi = lane >> 5;
  half8 mvh;
  {
    f32x4 ma = *(const f32x4*)(mean_vec + c8);
    f32x4 mb = *(const f32x4*)(mean_vec + c8 + 4);
    half4 h0 = pack4(ma), h1 = pack4(mb);
#pragma unroll
    for (int r = 0; r < 4; ++r) { mvh[r] = h0[r]; mvh[4 + r] = h1[r]; }
  }
  __syncthreads();   // rowoff/table visibility before staging reads it

  for (int ti = 0; ti < 4; ++ti) {
    const int s0 = ti * 64;
    const int cnt = min(64, SS_ - s0);

    // ---- stage x0 full-K: packed-f16 leaky(mean + conv1), b128 ops
    for (int it = 0; it < 4; ++it) {
      const int pos = 8 * wvs + it * 2 + lhi;
      const int srow = rowoff[min(s0 + pos, SS_ - 1)];
      half8 cv = *(const half8*)(conv1h + ((size_t)srow << 8) + c8);
      half8 t = cv + mvh;                       // v_pk_add_f16
      half8 s2 = t * (half_t)0.01f;             // v_pk_mul_f16
      half8 r8 = __builtin_elementwise_max(t, s2);  // v_pk_max_f16
      const int off = (pos * 512 + c8 * 2) ^ ((pos & 7) << 4);
      *(half8*)(lds + X0B + off) = r8;
    }
    __syncthreads();

    // ---- layer 1: 256 -> 128 MFMA (full K), W1 streamed
    f32x4 acc[4];
#pragma unroll
    for (int nt = 0; nt < 4; ++nt) acc[nt] = (f32x4){0.f, 0.f, 0.f, 0.f};
    {
      const half_t* w1p = w1base;
      asm volatile("" : "+v"(w1p));   // defeat hoisting across tiles
#pragma unroll 2
      for (int kb = 0; kb < 8; ++kb) {
        half8 a1 = *(const half8*)(w1p + kb * 32);
        const int kbyte = kb * 64 + ((lane >> 4) << 4);
#pragma unroll
        for (int nt = 0; nt < 4; ++nt) {
          const int pos = nt * 16 + (lane & 15);
          const int off = (pos * 512 + kbyte) ^ ((pos & 7) << 4);
          half8 bfr = *(const half8*)(lds + X0B + off);
          acc[nt] = __builtin_amdgcn_mfma_f32_16x16x32_f16(a1, bfr, acc[nt], 0, 0, 0);
        }
      }
#pragma unroll
      for (int nt = 0; nt < 4; ++nt) {
        const int pos = nt * 16 + (lane & 15);
        f32x4 a;
#pragma unroll
        for (int r = 0; r < 4; ++r) a[r] = fmaxf(acc[nt][r], 0.01f * acc[nt][r]);
        const int ch0 = 16 * wvs + ((lane >> 4) << 2);
        const int off = (pos * 256 + ch0 * 2) ^ ((pos & 7) << 4);
        *(half4*)(lds + X1B + off) = pack4(a);
      }
    }
    __syncthreads();

    // ---- layer 2: 128 -> 64 MFMA; epilogue -> x2 f16 [pos][64ch] swz (X0 region)
    f32x4 acc2[2];
#pragma unroll
    for (int nt = 0; nt < 2; ++nt) acc2[nt] = (f32x4){0.f, 0.f, 0.f, 0.f};
#pragma unroll
    for (int kb = 0; kb < 4; ++kb) {
      const int kbyte = kb * 64 + ((lane >> 4) << 4);
#pragma unroll
      for (int nt = 0; nt < 2; ++nt) {
        const int pos = h2w * 32 + nt * 16 + (lane & 15);
        const int off = (pos * 256 + kbyte) ^ ((pos & 7) << 4);
        half8 bfr = *(const half8*)(lds + X1B + off);
        acc2[nt] = __builtin_amdgcn_mfma_f32_16x16x32_f16(af2[kb], bfr, acc2[nt], 0, 0, 0);
      }
    }
#pragma unroll
    for (int nt = 0; nt < 2; ++nt) {
      const int pos = h2w * 32 + nt * 16 + (lane & 15);
      const int ch0 = 16 * g2 + ((lane >> 4) << 2);
      f32x4 a;
#pragma unroll
      for (int r = 0; r < 4; ++r) a[r] = fmaxf(acc2[nt][r], 0.01f * acc2[nt][r]);
      const int off = (pos * 128 + ch0 * 2) ^ ((pos & 7) << 4);
      *(half4*)(lds + X0B + off) = pack4(a);
    }
    __syncthreads();

    // ---- layer 3: 64 -> 32 MFMA; epilogue -> x3T f32 [pos][36f] (alias dead x1)
    {
      f32x4 acc3 = (f32x4){0.f, 0.f, 0.f, 0.f};
      const int pos = ct3 * 16 + (lane & 15);
#pragma unroll
      for (int kb = 0; kb < 2; ++kb) {
        half8 a3 = *(const half8*)(b3ptr + kb * 32);
        const int kbyte = kb * 64 + ((lane >> 4) << 4);
        const int off = (pos * 128 + kbyte) ^ ((pos & 7) << 4);
        half8 bfr = *(const half8*)(lds + X0B + off);
        acc3 = __builtin_amdgcn_mfma_f32_16x16x32_f16(a3, bfr, acc3, 0, 0, 0);
      }
      const int ch0 = 16 * rt3 + ((lane >> 4) << 2);
      f32x4 o4;
#pragma unroll
      for (int r = 0; r < 4; ++r) o4[r] = fmaxf(acc3[r], 0.01f * acc3[r]);
      *(f32x4*)(lds + X3TB + pos * 144 + ch0 * 4) = o4;
    }
    __syncthreads();

    // ---- layers 4-6, pos-sliced per wave (pos 8*wvs..+7), barrier-free
    {
      const int p = lane >> 3, g = lane & 7;
      const int pos = 8 * wvs + p;
      float a4_0 = 0.f, a4_1 = 0.f;
#pragma unroll
      for (int c0 = 0; c0 < 32; c0 += 4) {
        f32x4 x  = *(const f32x4*)(lds + X3TB + pos * 144 + c0 * 4);
        f32x4 wA = *(const f32x4*)(lds + W4B + (2 * g) * 144 + c0 * 4);
        f32x4 wB = *(const f32x4*)(lds + W4B + (2 * g + 1) * 144 + c0 * 4);
#pragma unroll
        for (int r = 0; r < 4; ++r) {
          a4_0 = fmaf(wA[r], x[r], a4_0);
          a4_1 = fmaf(wB[r], x[r], a4_1);
        }
      }
      f32x2 y4v;
      y4v[0] = fmaxf(a4_0, 0.01f * a4_0);
      y4v[1] = fmaxf(a4_1, 0.01f * a4_1);
      *(f32x2*)(lds + Y4B + pos * 80 + g * 8) = y4v;
      float a5 = 0.f;
#pragma unroll
      for (int c0 = 0; c0 < 16; c0 += 4) {
        f32x4 x = *(const f32x4*)(lds + Y4B + pos * 80 + c0 * 4);
        f32x4 w = *(const f32x4*)(lds + W5B + g * 80 + c0 * 4);
#pragma unroll
        for (int r = 0; r < 4; ++r) a5 = fmaf(w[r], x[r], a5);
      }
      a5 = fmaxf(a5, 0.01f * a5);
      float t6 = ((float*)(lds + W6B))[g] * a5;
      t6 += __shfl_xor(t6, 1);
      t6 += __shfl_xor(t6, 2);
      t6 += __shfl_xor(t6, 4);
      if (g == 0 && (8 * wvs + p) < cnt) sm[s0 + pos] = t6;
    }
    __syncthreads();
  }

  // ---- softmax over 225 logits
  float vv = (tid < SS_) ? sm[tid] : -1e30f;
  float m = vv;
#pragma unroll
  for (int off = 32; off >= 1; off >>= 1) m = fmaxf(m, __shfl_xor(m, off));
  if (lane == 0) red[wvs] = m;
  __syncthreads();
  m = red[0];
#pragma unroll
  for (int w = 1; w < 8; ++w) m = fmaxf(m, red[w]);
  float e = (tid < SS_) ? __expf(vv - m) : 0.f;
  float ss = e;
#pragma unroll
  for (int off = 32; off >= 1; off >>= 1) ss += __shfl_xor(ss, off);
  __syncthreads();
  if (lane == 0) red[wvs] = ss;
  __syncthreads();
  float Stot = red[0];
#pragma unroll
  for (int w = 1; w < 8; ++w) Stot += red[w];
  if (tid < SS_) sm[tid] = e / Stot;
  __syncthreads();

  // ---- weighted channel sum: 2 channels/thread (f16 features), 4-way pos split
  {
    const int c2 = (tid & 127) * 2;
    const int q  = tid >> 7;          // 0..3
    float accx = 0.f, accy = 0.f;
    for (int s = q; s < SS_; s += 4) {
      h2 ft = *(const h2*)(inarrh + ((size_t)rowoff[s] << 8) + c2);
      float w = sm[s];
      accx = fmaf(w, (float)ft[0], accx);
      accy = fmaf(w, (float)ft[1], accy);
    }
    __syncthreads();
    ldsf[q * 256 + c2]     = accx;
    ldsf[q * 256 + c2 + 1] = accy;
    __syncthreads();
    if (tid < 256) {
      float tot = ldsf[tid] + ldsf[256 + tid] + ldsf[512 + tid] + ldsf[768 + tid];
      if (!is_t) out[2048 + ((size_t)(b * 256 + tid) * 17 + u) * 17 + v] = tot;
      else       out[b * 256 + tid] = tot;
    }
  }
}

// ---------------------------------------------------------------------------
extern "C" void kernel_launch(void* const* d_in, const int* in_sizes, int n_in,
                              void* d_out, int out_size, void* d_ws, size_t ws_size,
                              hipStream_t stream)
{
  const float* templ = (const float*)d_in[0];
  const float* cand  = (const float*)d_in[1];
  const float* w0 = (const float*)d_in[2];
  const float* w1 = (const float*)d_in[3];
  const float* w2 = (const float*)d_in[4];
  const float* w3 = (const float*)d_in[5];
  const float* w4 = (const float*)d_in[6];
  const float* w5 = (const float*)d_in[7];
  const float* w6 = (const float*)d_in[8];

  float* ws    = (float*)d_ws;
  float* gout  = ws + OFF_GOUT;
  float* rows  = ws + OFF_ROWS;
  float* m0v   = ws + OFF_M0;
  float* tm0v  = ws + OFF_TM0;
  half_t* inarrh = (half_t*)(ws + OFF_F16);
  half_t* conv1h = inarrh + (size_t)NROW * 256;
  half_t* w0h  = conv1h + (size_t)NROW * 256;
  half_t* w1h  = w0h + NW0H;
  half_t* w2h  = w1h + 128 * 256;
  half_t* w3h  = w2h + 64 * 128;
  float* outf  = (float*)d_out;

  featT_kernel<<<B_ * 31 + B_ * 8, 256, 0, stream>>>(templ, cand, inarrh);
  wcvt_kernel<<<256, 256, 0, stream>>>(w0, w1, w2, w3, w0h, w1h, w2h, w3h);
  l0gemm_kernel<<<NROW / 16, 512, 0, stream>>>(inarrh, w0h, conv1h, gout);
  rowsum_kernel<<<B_ * 31 * 17, 256, 0, stream>>>(gout, rows);
  colsum_kernel<<<B_ * KK_, 256, 0, stream>>>(rows, m0v);
  tmean0_kernel<<<B_, 256, 0, stream>>>(gout, tm0v);
  chain_kernel<<<B_ * KK_ + B_, 512, 0, stream>>>(conv1h, m0v, tm0v,
                                                  w1h, w2h, w3h, w4, w5, w6,
                                                  inarrh, outf);
}

// Round 18
// 256.566 us; speedup vs baseline: 1.9429x; 1.0486x over previous
//
#include <hip/hip_runtime.h>

typedef _Float16 half_t;
typedef half_t h2    __attribute__((ext_vector_type(2)));
typedef half_t half4 __attribute__((ext_vector_type(4)));
typedef half_t half8 __attribute__((ext_vector_type(8)));
typedef __fp16 pk16x2 __attribute__((ext_vector_type(2)));
typedef float  f32x4 __attribute__((ext_vector_type(4)));
typedef float  f32x2 __attribute__((ext_vector_type(2)));

static __device__ __forceinline__ half4 pack4(f32x4 a) {
  pk16x2 lo = __builtin_amdgcn_cvt_pkrtz(a[0], a[1]);
  pk16x2 hi = __builtin_amdgcn_cvt_pkrtz(a[2], a[3]);
  half4 h;
  h[0] = lo[0]; h[1] = lo[1]; h[2] = hi[0]; h[3] = hi[1];
  return h;
}

constexpr int B_  = 8;
constexpr int S_  = 15;
constexpr int K_  = 17;
constexpr int P_  = 31;
constexpr int SS_ = 225;
constexpr int PP_ = 961;
constexpr int KK_ = 289;

constexpr int NROW_C = B_ * PP_;          // 7688
constexpr int NROW_T = B_ * SS_;          // 1800
constexpr int NROW   = NROW_C + NROW_T;   // 9488 = 593*16

constexpr int NW0H = 512 * 256;
constexpr int NF16 = 128*256 + 64*128 + 32*64;
constexpr int NFEATB = B_ * 31 + B_ * 8;  // 248 featT blocks

// workspace float offsets
constexpr size_t OFF_GOUT = 0;
constexpr size_t OFF_ROWS = OFF_GOUT + (size_t)NROW * 256;
constexpr size_t OFF_M0   = OFF_ROWS + (size_t)B_ * 31 * 17 * 256;
constexpr size_t OFF_TM0  = OFF_M0   + (size_t)B_ * KK_ * 256;
constexpr size_t OFF_F16  = OFF_TM0  + (size_t)B_ * 256;

// chain LDS byte offsets (53,632 B -> 3 blocks/CU)
constexpr int X0B  = 0;       // f16 x0 [64][512B] swz (x2 aliases; final reduce)
constexpr int X1B  = 32768;   // f16 x1 [64][256B] swz
constexpr int X3TB = 32768;   // f32 x3T [64][36f] (alias dead x1)
constexpr int Y4B  = 41984;   // f32 y4T [64][20f] (alias dead x1)
constexpr int SMB  = 49152;   // 240 f logits
constexpr int REDB = 50112;   // 16 f
constexpr int W4B  = 50176;   // w4 [16][36f]
constexpr int W5B  = 52480;   // w5 [8][20f]
constexpr int W6B  = 53120;   // w6 [8]
constexpr int ROWB = 53152;   // 225 u16 row table
constexpr int LDSB = 53632;

// ---------------------------------------------------------------------------
// fused prep: featT blocks (0..247) + wcvt blocks (248..)
// ---------------------------------------------------------------------------
__global__ __launch_bounds__(256) void prep_kernel(
    const float* __restrict__ templ, const float* __restrict__ cand,
    const float* __restrict__ w0, const float* __restrict__ w1,
    const float* __restrict__ w2, const float* __restrict__ w3,
    half_t* __restrict__ inarrh, half_t* __restrict__ w0h,
    half_t* __restrict__ w1h, half_t* __restrict__ w2h,
    half_t* __restrict__ w3h)
{
  __shared__ float tile[32 * 257];
  const int bid = blockIdx.x;
  const int tid = threadIdx.x;
  if (bid < NFEATB) {
    const float* src;
    int base, npos, rowbase, stride;
    if (bid < B_ * 31) {
      int b = bid / 31, ch = bid % 31;
      src = cand + (size_t)b * 256 * PP_;
      base = ch * 32; npos = min(32, PP_ - base);
      rowbase = b * PP_ + base; stride = PP_;
    } else {
      int t = bid - B_ * 31;
      int b = t / 8, ch = t % 8;
      src = templ + (size_t)b * 256 * SS_;
      base = ch * 32; npos = min(32, SS_ - base);
      rowbase = NROW_C + b * SS_ + base; stride = SS_;
    }
    const int p  = tid & 31;
    const int c8 = tid >> 5;
    if (p < npos) {
      for (int it = 0; it < 32; ++it) {
        int c = c8 * 32 + it;
        tile[p * 257 + c] = src[(size_t)c * stride + base + p];
      }
    }
    __syncthreads();
    for (int pp = 0; pp < npos; ++pp)
      inarrh[(size_t)(rowbase + pp) * 256 + tid] = (half_t)tile[pp * 257 + tid];
  } else {
    const int nb = gridDim.x - NFEATB;
    const int wb = bid - NFEATB;
    const int total = NW0H + NF16;
    for (int idx = wb * 256 + tid; idx < total; idx += nb * 256) {
      if (idx < NW0H) {
        int m = idx >> 8; int c = idx & 255;
        w0h[idx] = (half_t)(m < 256 ? w0[m * 512 + 256 + c] : w0[(m - 256) * 512 + c]);
      } else {
        int t = idx - NW0H;
        if (t < 32768)      w1h[t] = (half_t)w1[t];
        else if (t < 40960) w2h[t - 32768] = (half_t)w2[t - 32768];
        else                w3h[t - 40960] = (half_t)w3[t - 40960];
      }
    }
  }
}

// ---------------------------------------------------------------------------
__global__ __launch_bounds__(512) void l0gemm_kernel(
    const half_t* __restrict__ inh, const half_t* __restrict__ w0h,
    half_t* __restrict__ conv1h, float* __restrict__ gout)
{
  __shared__ __align__(16) char xls[16 * 512];
  const int tid  = threadIdx.x;
  const int lane = tid & 63;
  const int wvs  = tid >> 6;
  const int row0 = blockIdx.x * 16;

  {
    const int row = tid >> 5;
    const int c8  = (tid & 31) * 8;
    half8 h = *(const half8*)(inh + (size_t)(row0 + row) * 256 + c8);
    const int off = (row * 512 + c8 * 2) ^ ((row & 7) << 4);
    *(half8*)(xls + off) = h;
  }
  __syncthreads();

  const int l15 = lane & 15, g = lane >> 4;
  f32x4 acc[4];
#pragma unroll
  for (int mt = 0; mt < 4; ++mt) acc[mt] = (f32x4){0.f, 0.f, 0.f, 0.f};
#pragma unroll 2
  for (int kb = 0; kb < 8; ++kb) {
    const int off = (l15 * 512 + kb * 64 + g * 16) ^ ((l15 & 7) << 4);
    half8 bfr = *(const half8*)(xls + off);
#pragma unroll
    for (int mt = 0; mt < 4; ++mt) {
      const half_t* ap = w0h + (size_t)((wvs * 4 + mt) * 16 + l15) * 256 + kb * 32 + g * 8;
      half8 a = *(const half8*)ap;
      acc[mt] = __builtin_amdgcn_mfma_f32_16x16x32_f16(a, bfr, acc[mt], 0, 0, 0);
    }
  }
#pragma unroll
  for (int mt = 0; mt < 4; ++mt) {
    const int m0c = (wvs * 4 + mt) * 16 + g * 4;
    if (wvs < 4)
      *(half4*)(conv1h + (size_t)(row0 + l15) * 256 + m0c) = pack4(acc[mt]);
    else
      *(f32x4*)(gout + (size_t)(row0 + l15) * 256 + (m0c - 256)) = acc[mt];
  }
}

// ---------------------------------------------------------------------------
__global__ __launch_bounds__(256) void rowsum_kernel(
    const float* __restrict__ gout, float* __restrict__ rows)
{
  const int bid = blockIdx.x;
  const int o = threadIdx.x;
  const int v = bid % 17; const int p = (bid / 17) % 31; const int b = bid / (17 * 31);
  float s = 0.f;
  for (int j = 0; j < 15; ++j)
    s += gout[(size_t)(b * PP_ + p * P_ + v + j) * 256 + o];
  rows[(size_t)bid * 256 + o] = s;
}

// fused colsum + tmean0
__global__ __launch_bounds__(256) void colsum_tmean_kernel(
    const float* __restrict__ rows, const float* __restrict__ gout,
    float* __restrict__ m0v, float* __restrict__ tm0v)
{
  const int bid = blockIdx.x;
  const int o = threadIdx.x;
  if (bid < B_ * KK_) {
    const int v = bid % 17; const int u = (bid / 17) % 17; const int b = bid / KK_;
    float s = 0.f;
    for (int i = 0; i < 15; ++i)
      s += rows[(size_t)((b * 31 + u + i) * 17 + v) * 256 + o];
    m0v[(size_t)bid * 256 + o] = s * (1.0f / 225.0f);
  } else {
    const int b = bid - B_ * KK_;
    float s = 0.f;
    for (int t = 0; t < SS_; ++t)
      s += gout[(size_t)(NROW_C + b * SS_ + t) * 256 + o];
    tm0v[b * 256 + o] = s * (1.0f / 225.0f);
  }
}

// ---------------------------------------------------------------------------
__global__ __launch_bounds__(512, 4) void chain_kernel(
    const half_t* __restrict__ conv1h, const float* __restrict__ m0v,
    const float* __restrict__ tm0v,
    const half_t* __restrict__ w1h, const half_t* __restrict__ w2h,
    const half_t* __restrict__ w3h,
    const float* __restrict__ w4, const float* __restrict__ w5,
    const float* __restrict__ w6,
    const half_t* __restrict__ inarrh, float* __restrict__ out)
{
  __shared__ __align__(16) char lds[LDSB];
  float*    ldsf   = (float*)lds;
  float*    sm     = (float*)(lds + SMB);
  float*    red    = (float*)(lds + REDB);
  uint16_t* rowoff = (uint16_t*)(lds + ROWB);

  const int tid  = threadIdx.x;
  const int lane = tid & 63;
  const int wvs  = __builtin_amdgcn_readfirstlane(tid >> 6);
  const int bid  = (blockIdx.x & 7) * 290 + (blockIdx.x >> 3);
  const bool is_t = (bid >= B_ * KK_);
  int b, u = 0, v = 0;
  const float* mean_vec;
  if (!is_t) {
    b = bid / KK_;
    int r = bid % KK_;
    u = r / K_; v = r % K_;
    mean_vec = m0v + (size_t)bid * 256;
  } else {
    b = bid - B_ * KK_;
    mean_vec = tm0v + (size_t)b * 256;
  }

  if (tid < SS_) {
    int i = tid / 15, j = tid - i * 15;
    rowoff[tid] = is_t ? (uint16_t)(NROW_C + b * SS_ + tid)
                       : (uint16_t)(b * PP_ + (u + i) * P_ + (v + j));
  }
  ((float*)(lds + W4B))[(tid >> 5) * 36 + (tid & 31)] = w4[tid];
  if (tid < 128) ((float*)(lds + W5B))[(tid >> 4) * 20 + (tid & 15)] = w5[tid];
  if (tid < 8)   ((float*)(lds + W6B))[tid] = w6[tid];

  const half_t* w1base = w1h + (size_t)(16 * wvs + (lane & 15)) * 256 + ((lane >> 4) << 3);
  const int g2 = wvs & 3, h2w = wvs >> 2;
  half8 af2[4];
  {
    const half_t* base = w2h + (size_t)(16 * g2 + (lane & 15)) * 128 + ((lane >> 4) << 3);
#pragma unroll
    for (int kb = 0; kb < 4; ++kb) af2[kb] = *(const half8*)(base + kb * 32);
  }
  const int rt3 = wvs & 1, ct3 = wvs >> 1;
  const half_t* b3ptr = w3h + (size_t)(16 * rt3 + (lane & 15)) * 64 + ((lane >> 4) << 3);
  const int c8  = (lane & 31) * 8;
  const int lhi = lane >> 5;
  half8 mvh;
  {
    f32x4 ma = *(const f32x4*)(mean_vec + c8);
    f32x4 mb = *(const f32x4*)(mean_vec + c8 + 4);
    half4 h0 = pack4(ma), h1 = pack4(mb);
#pragma unroll
    for (int r = 0; r < 4; ++r) { mvh[r] = h0[r]; mvh[4 + r] = h1[r]; }
  }
  __syncthreads();   // rowoff visibility

  // stage helper (computes leaky(cv+mean) and writes swizzled LDS)
  auto stage_write = [&](int pos, half8 cv) {
    half8 t = cv + mvh;
    half8 s2 = t * (half_t)0.01f;
    half8 r8 = __builtin_elementwise_max(t, s2);
    const int off = (pos * 512 + c8 * 2) ^ ((pos & 7) << 4);
    *(half8*)(lds + X0B + off) = r8;
  };

  // prologue: stage tile 0
  {
    const int pbase = 8 * wvs + lhi;
#pragma unroll
    for (int it = 0; it < 4; ++it) {
      const int pos = pbase + it * 2;
      const int srow = rowoff[min(pos, SS_ - 1)];
      half8 cv = *(const half8*)(conv1h + ((size_t)srow << 8) + c8);
      stage_write(pos, cv);
    }
  }
  __syncthreads();

  for (int ti = 0; ti < 4; ++ti) {
    const int s0 = ti * 64;
    const int cnt = min(64, SS_ - s0);

    // ---- layer 1: 256 -> 128 MFMA (full K), W1 streamed
    f32x4 acc[4];
#pragma unroll
    for (int nt = 0; nt < 4; ++nt) acc[nt] = (f32x4){0.f, 0.f, 0.f, 0.f};
    {
      const half_t* w1p = w1base;
      asm volatile("" : "+v"(w1p));
#pragma unroll 2
      for (int kb = 0; kb < 8; ++kb) {
        half8 a1 = *(const half8*)(w1p + kb * 32);
        const int kbyte = kb * 64 + ((lane >> 4) << 4);
#pragma unroll
        for (int nt = 0; nt < 4; ++nt) {
          const int pos = nt * 16 + (lane & 15);
          const int off = (pos * 512 + kbyte) ^ ((pos & 7) << 4);
          half8 bfr = *(const half8*)(lds + X0B + off);
          acc[nt] = __builtin_amdgcn_mfma_f32_16x16x32_f16(a1, bfr, acc[nt], 0, 0, 0);
        }
      }
#pragma unroll
      for (int nt = 0; nt < 4; ++nt) {
        const int pos = nt * 16 + (lane & 15);
        f32x4 a;
#pragma unroll
        for (int r = 0; r < 4; ++r) a[r] = fmaxf(acc[nt][r], 0.01f * acc[nt][r]);
        const int ch0 = 16 * wvs + ((lane >> 4) << 2);
        const int off = (pos * 256 + ch0 * 2) ^ ((pos & 7) << 4);
        *(half4*)(lds + X1B + off) = pack4(a);
      }
    }
    __syncthreads();

    // ---- layer 2: 128 -> 64 MFMA; epilogue -> x2 f16 (X0 region)
    f32x4 acc2[2];
#pragma unroll
    for (int nt = 0; nt < 2; ++nt) acc2[nt] = (f32x4){0.f, 0.f, 0.f, 0.f};
#pragma unroll
    for (int kb = 0; kb < 4; ++kb) {
      const int kbyte = kb * 64 + ((lane >> 4) << 4);
#pragma unroll
      for (int nt = 0; nt < 2; ++nt) {
        const int pos = h2w * 32 + nt * 16 + (lane & 15);
        const int off = (pos * 256 + kbyte) ^ ((pos & 7) << 4);
        half8 bfr = *(const half8*)(lds + X1B + off);
        acc2[nt] = __builtin_amdgcn_mfma_f32_16x16x32_f16(af2[kb], bfr, acc2[nt], 0, 0, 0);
      }
    }
#pragma unroll
    for (int nt = 0; nt < 2; ++nt) {
      const int pos = h2w * 32 + nt * 16 + (lane & 15);
      const int ch0 = 16 * g2 + ((lane >> 4) << 2);
      f32x4 a;
#pragma unroll
      for (int r = 0; r < 4; ++r) a[r] = fmaxf(acc2[nt][r], 0.01f * acc2[nt][r]);
      const int off = (pos * 128 + ch0 * 2) ^ ((pos & 7) << 4);
      *(half4*)(lds + X0B + off) = pack4(a);
    }
    __syncthreads();

    // ---- layer 3: 64 -> 32 MFMA; epilogue -> x3T f32 [pos][36f]
    {
      f32x4 acc3 = (f32x4){0.f, 0.f, 0.f, 0.f};
      const int pos = ct3 * 16 + (lane & 15);
#pragma unroll
      for (int kb = 0; kb < 2; ++kb) {
        half8 a3 = *(const half8*)(b3ptr + kb * 32);
        const int kbyte = kb * 64 + ((lane >> 4) << 4);
        const int off = (pos * 128 + kbyte) ^ ((pos & 7) << 4);
        half8 bfr = *(const half8*)(lds + X0B + off);
        acc3 = __builtin_amdgcn_mfma_f32_16x16x32_f16(a3, bfr, acc3, 0, 0, 0);
      }
      const int ch0 = 16 * rt3 + ((lane >> 4) << 2);
      f32x4 o4;
#pragma unroll
      for (int r = 0; r < 4; ++r) o4[r] = fmaxf(acc3[r], 0.01f * acc3[r]);
      *(f32x4*)(lds + X3TB + pos * 144 + ch0 * 4) = o4;
    }
    __syncthreads();

    // ---- tail (layers 4-6) + async stage(ti+1): loads issued early,
    //      x2 (X0 region) is dead; stage writes land after tail compute
    {
      half8 cv0, cv1, cv2, cv3;
      const int pbase = 8 * wvs + lhi;
      if (ti < 3) {
        const int s1 = s0 + 64;
        cv0 = *(const half8*)(conv1h + ((size_t)rowoff[min(s1 + pbase,     SS_ - 1)] << 8) + c8);
        cv1 = *(const half8*)(conv1h + ((size_t)rowoff[min(s1 + pbase + 2, SS_ - 1)] << 8) + c8);
        cv2 = *(const half8*)(conv1h + ((size_t)rowoff[min(s1 + pbase + 4, SS_ - 1)] << 8) + c8);
        cv3 = *(const half8*)(conv1h + ((size_t)rowoff[min(s1 + pbase + 6, SS_ - 1)] << 8) + c8);
      }

      const int p = lane >> 3, g = lane & 7;
      const int pos = 8 * wvs + p;
      float a4_0 = 0.f, a4_1 = 0.f;
#pragma unroll
      for (int c0 = 0; c0 < 32; c0 += 4) {
        f32x4 x  = *(const f32x4*)(lds + X3TB + pos * 144 + c0 * 4);
        f32x4 wA = *(const f32x4*)(lds + W4B + (2 * g) * 144 + c0 * 4);
        f32x4 wB = *(const f32x4*)(lds + W4B + (2 * g + 1) * 144 + c0 * 4);
#pragma unroll
        for (int r = 0; r < 4; ++r) {
          a4_0 = fmaf(wA[r], x[r], a4_0);
          a4_1 = fmaf(wB[r], x[r], a4_1);
        }
      }
      f32x2 y4v;
      y4v[0] = fmaxf(a4_0, 0.01f * a4_0);
      y4v[1] = fmaxf(a4_1, 0.01f * a4_1);
      *(f32x2*)(lds + Y4B + pos * 80 + g * 8) = y4v;
      float a5 = 0.f;
#pragma unroll
      for (int c0 = 0; c0 < 16; c0 += 4) {
        f32x4 x = *(const f32x4*)(lds + Y4B + pos * 80 + c0 * 4);
        f32x4 w = *(const f32x4*)(lds + W5B + g * 80 + c0 * 4);
#pragma unroll
        for (int r = 0; r < 4; ++r) a5 = fmaf(w[r], x[r], a5);
      }
      a5 = fmaxf(a5, 0.01f * a5);
      float t6 = ((float*)(lds + W6B))[g] * a5;
      t6 += __shfl_xor(t6, 1);
      t6 += __shfl_xor(t6, 2);
      t6 += __shfl_xor(t6, 4);
      if (g == 0 && pos < cnt) sm[s0 + pos] = t6;

      if (ti < 3) {
        stage_write(pbase,     cv0);
        stage_write(pbase + 2, cv1);
        stage_write(pbase + 4, cv2);
        stage_write(pbase + 6, cv3);
      }
    }
    __syncthreads();
  }

  // ---- softmax over 225 logits
  float vv = (tid < SS_) ? sm[tid] : -1e30f;
  float m = vv;
#pragma unroll
  for (int off = 32; off >= 1; off >>= 1) m = fmaxf(m, __shfl_xor(m, off));
  if (lane == 0) red[wvs] = m;
  __syncthreads();
  m = red[0];
#pragma unroll
  for (int w = 1; w < 8; ++w) m = fmaxf(m, red[w]);
  float e = (tid < SS_) ? __expf(vv - m) : 0.f;
  float ss = e;
#pragma unroll
  for (int off = 32; off >= 1; off >>= 1) ss += __shfl_xor(ss, off);
  __syncthreads();
  if (lane == 0) red[wvs] = ss;
  __syncthreads();
  float Stot = red[0];
#pragma unroll
  for (int w = 1; w < 8; ++w) Stot += red[w];
  if (tid < SS_) sm[tid] = e / Stot;
  __syncthreads();

  // ---- weighted channel sum: 2 channels/thread (f16 features), 4-way pos split
  {
    const int c2 = (tid & 127) * 2;
    const int q  = tid >> 7;
    float accx = 0.f, accy = 0.f;
    for (int s = q; s < SS_; s += 4) {
      h2 ft = *(const h2*)(inarrh + ((size_t)rowoff[s] << 8) + c2);
      float w = sm[s];
      accx = fmaf(w, (float)ft[0], accx);
      accy = fmaf(w, (float)ft[1], accy);
    }
    __syncthreads();
    ldsf[q * 256 + c2]     = accx;
    ldsf[q * 256 + c2 + 1] = accy;
    __syncthreads();
    if (tid < 256) {
      float tot = ldsf[tid] + ldsf[256 + tid] + ldsf[512 + tid] + ldsf[768 + tid];
      if (!is_t) out[2048 + ((size_t)(b * 256 + tid) * 17 + u) * 17 + v] = tot;
      else       out[b * 256 + tid] = tot;
    }
  }
}

// ---------------------------------------------------------------------------
extern "C" void kernel_launch(void* const* d_in, const int* in_sizes, int n_in,
                              void* d_out, int out_size, void* d_ws, size_t ws_size,
                              hipStream_t stream)
{
  const float* templ = (const float*)d_in[0];
  const float* cand  = (const float*)d_in[1];
  const float* w0 = (const float*)d_in[2];
  const float* w1 = (const float*)d_in[3];
  const float* w2 = (const float*)d_in[4];
  const float* w3 = (const float*)d_in[5];
  const float* w4 = (const float*)d_in[6];
  const float* w5 = (const float*)d_in[7];
  const float* w6 = (const float*)d_in[8];

  float* ws    = (float*)d_ws;
  float* gout  = ws + OFF_GOUT;
  float* rows  = ws + OFF_ROWS;
  float* m0v   = ws + OFF_M0;
  float* tm0v  = ws + OFF_TM0;
  half_t* inarrh = (half_t*)(ws + OFF_F16);
  half_t* conv1h = inarrh + (size_t)NROW * 256;
  half_t* w0h  = conv1h + (size_t)NROW * 256;
  half_t* w1h  = w0h + NW0H;
  half_t* w2h  = w1h + 128 * 256;
  half_t* w3h  = w2h + 64 * 128;
  float* outf  = (float*)d_out;

  prep_kernel<<<NFEATB + 88, 256, 0, stream>>>(templ, cand, w0, w1, w2, w3,
                                               inarrh, w0h, w1h, w2h, w3h);
  l0gemm_kernel<<<NROW / 16, 512, 0, stream>>>(inarrh, w0h, conv1h, gout);
  rowsum_kernel<<<B_ * 31 * 17, 256, 0, stream>>>(gout, rows);
  colsum_tmean_kernel<<<B_ * KK_ + B_, 256, 0, stream>>>(rows, gout, m0v, tm0v);
  chain_kernel<<<B_ * KK_ + B_, 512, 0, stream>>>(conv1h, m0v, tm0v,
                                                  w1h, w2h, w3h, w4, w5, w6,
                                                  inarrh, outf);
}

// Round 19
// 250.548 us; speedup vs baseline: 1.9896x; 1.0240x over previous
//
#include <hip/hip_runtime.h>

typedef _Float16 half_t;
typedef half_t h2    __attribute__((ext_vector_type(2)));
typedef half_t half4 __attribute__((ext_vector_type(4)));
typedef half_t half8 __attribute__((ext_vector_type(8)));
typedef __fp16 pk16x2 __attribute__((ext_vector_type(2)));
typedef float  f32x4 __attribute__((ext_vector_type(4)));
typedef float  f32x2 __attribute__((ext_vector_type(2)));

template <int N> struct IC { static constexpr int value = N; };

static __device__ __forceinline__ half4 pack4(f32x4 a) {
  pk16x2 lo = __builtin_amdgcn_cvt_pkrtz(a[0], a[1]);
  pk16x2 hi = __builtin_amdgcn_cvt_pkrtz(a[2], a[3]);
  half4 h;
  h[0] = lo[0]; h[1] = lo[1]; h[2] = hi[0]; h[3] = hi[1];
  return h;
}

constexpr int B_  = 8;
constexpr int S_  = 15;
constexpr int K_  = 17;
constexpr int P_  = 31;
constexpr int SS_ = 225;
constexpr int PP_ = 961;
constexpr int KK_ = 289;

constexpr int NROW_C = B_ * PP_;          // 7688
constexpr int NROW_T = B_ * SS_;          // 1800
constexpr int NROW   = NROW_C + NROW_T;   // 9488 = 593*16

constexpr int NW0H = 512 * 256;
constexpr int NF16 = 128*256 + 64*128 + 32*64;
constexpr int NFEATB = B_ * 31 + B_ * 8;  // 248 featT blocks

// workspace float offsets
constexpr size_t OFF_GOUT = 0;
constexpr size_t OFF_ROWS = OFF_GOUT + (size_t)NROW * 256;
constexpr size_t OFF_M0   = OFF_ROWS + (size_t)B_ * 31 * 17 * 256;
constexpr size_t OFF_TM0  = OFF_M0   + (size_t)B_ * KK_ * 256;
constexpr size_t OFF_F16  = OFF_TM0  + (size_t)B_ * 256;

// chain LDS byte offsets (53,632 B -> 3 blocks/CU)
constexpr int X0B  = 0;       // f16 x0 [64][512B] swz (x2 aliases; final reduce)
constexpr int X1B  = 32768;   // f16 x1 [64][256B] swz
constexpr int X3TB = 32768;   // f32 x3T [64][36f] (alias dead x1)
constexpr int Y4B  = 41984;   // f32 y4T [64][20f] (alias dead x1)
constexpr int SMB  = 49152;   // 240 f logits
constexpr int REDB = 50112;   // 16 f
constexpr int W4B  = 50176;   // w4 [16][36f]
constexpr int W5B  = 52480;   // w5 [8][20f]
constexpr int W6B  = 53120;   // w6 [8]
constexpr int ROWB = 53152;   // 225 u16 row table
constexpr int LDSB = 53632;

// ---------------------------------------------------------------------------
// fused prep: featT blocks (0..247) + wcvt blocks (248..)
// ---------------------------------------------------------------------------
__global__ __launch_bounds__(256) void prep_kernel(
    const float* __restrict__ templ, const float* __restrict__ cand,
    const float* __restrict__ w0, const float* __restrict__ w1,
    const float* __restrict__ w2, const float* __restrict__ w3,
    half_t* __restrict__ inarrh, half_t* __restrict__ w0h,
    half_t* __restrict__ w1h, half_t* __restrict__ w2h,
    half_t* __restrict__ w3h)
{
  __shared__ float tile[32 * 257];
  const int bid = blockIdx.x;
  const int tid = threadIdx.x;
  if (bid < NFEATB) {
    const float* src;
    int base, npos, rowbase, stride;
    if (bid < B_ * 31) {
      int b = bid / 31, ch = bid % 31;
      src = cand + (size_t)b * 256 * PP_;
      base = ch * 32; npos = min(32, PP_ - base);
      rowbase = b * PP_ + base; stride = PP_;
    } else {
      int t = bid - B_ * 31;
      int b = t / 8, ch = t % 8;
      src = templ + (size_t)b * 256 * SS_;
      base = ch * 32; npos = min(32, SS_ - base);
      rowbase = NROW_C + b * SS_ + base; stride = SS_;
    }
    const int p  = tid & 31;
    const int c8 = tid >> 5;
    if (p < npos) {
      for (int it = 0; it < 32; ++it) {
        int c = c8 * 32 + it;
        tile[p * 257 + c] = src[(size_t)c * stride + base + p];
      }
    }
    __syncthreads();
    for (int pp = 0; pp < npos; ++pp)
      inarrh[(size_t)(rowbase + pp) * 256 + tid] = (half_t)tile[pp * 257 + tid];
  } else {
    const int nb = gridDim.x - NFEATB;
    const int wb = bid - NFEATB;
    const int total = NW0H + NF16;
    for (int idx = wb * 256 + tid; idx < total; idx += nb * 256) {
      if (idx < NW0H) {
        int m = idx >> 8; int c = idx & 255;
        w0h[idx] = (half_t)(m < 256 ? w0[m * 512 + 256 + c] : w0[(m - 256) * 512 + c]);
      } else {
        int t = idx - NW0H;
        if (t < 32768)      w1h[t] = (half_t)w1[t];
        else if (t < 40960) w2h[t - 32768] = (half_t)w2[t - 32768];
        else                w3h[t - 40960] = (half_t)w3[t - 40960];
      }
    }
  }
}

// ---------------------------------------------------------------------------
__global__ __launch_bounds__(512) void l0gemm_kernel(
    const half_t* __restrict__ inh, const half_t* __restrict__ w0h,
    half_t* __restrict__ conv1h, float* __restrict__ gout)
{
  __shared__ __align__(16) char xls[16 * 512];
  const int tid  = threadIdx.x;
  const int lane = tid & 63;
  const int wvs  = tid >> 6;
  const int row0 = blockIdx.x * 16;

  {
    const int row = tid >> 5;
    const int c8  = (tid & 31) * 8;
    half8 h = *(const half8*)(inh + (size_t)(row0 + row) * 256 + c8);
    const int off = (row * 512 + c8 * 2) ^ ((row & 7) << 4);
    *(half8*)(xls + off) = h;
  }
  __syncthreads();

  const int l15 = lane & 15, g = lane >> 4;
  f32x4 acc[4];
#pragma unroll
  for (int mt = 0; mt < 4; ++mt) acc[mt] = (f32x4){0.f, 0.f, 0.f, 0.f};
#pragma unroll 2
  for (int kb = 0; kb < 8; ++kb) {
    const int off = (l15 * 512 + kb * 64 + g * 16) ^ ((l15 & 7) << 4);
    half8 bfr = *(const half8*)(xls + off);
#pragma unroll
    for (int mt = 0; mt < 4; ++mt) {
      const half_t* ap = w0h + (size_t)((wvs * 4 + mt) * 16 + l15) * 256 + kb * 32 + g * 8;
      half8 a = *(const half8*)ap;
      acc[mt] = __builtin_amdgcn_mfma_f32_16x16x32_f16(a, bfr, acc[mt], 0, 0, 0);
    }
  }
#pragma unroll
  for (int mt = 0; mt < 4; ++mt) {
    const int m0c = (wvs * 4 + mt) * 16 + g * 4;
    if (wvs < 4)
      *(half4*)(conv1h + (size_t)(row0 + l15) * 256 + m0c) = pack4(acc[mt]);
    else
      *(f32x4*)(gout + (size_t)(row0 + l15) * 256 + (m0c - 256)) = acc[mt];
  }
}

// ---------------------------------------------------------------------------
__global__ __launch_bounds__(256) void rowsum_kernel(
    const float* __restrict__ gout, float* __restrict__ rows)
{
  const int bid = blockIdx.x;
  const int o = threadIdx.x;
  const int v = bid % 17; const int p = (bid / 17) % 31; const int b = bid / (17 * 31);
  float s = 0.f;
  for (int j = 0; j < 15; ++j)
    s += gout[(size_t)(b * PP_ + p * P_ + v + j) * 256 + o];
  rows[(size_t)bid * 256 + o] = s;
}

__global__ __launch_bounds__(256) void colsum_tmean_kernel(
    const float* __restrict__ rows, const float* __restrict__ gout,
    float* __restrict__ m0v, float* __restrict__ tm0v)
{
  const int bid = blockIdx.x;
  const int o = threadIdx.x;
  if (bid < B_ * KK_) {
    const int v = bid % 17; const int u = (bid / 17) % 17; const int b = bid / KK_;
    float s = 0.f;
    for (int i = 0; i < 15; ++i)
      s += rows[(size_t)((b * 31 + u + i) * 17 + v) * 256 + o];
    m0v[(size_t)bid * 256 + o] = s * (1.0f / 225.0f);
  } else {
    const int b = bid - B_ * KK_;
    float s = 0.f;
    for (int t = 0; t < SS_; ++t)
      s += gout[(size_t)(NROW_C + b * SS_ + t) * 256 + o];
    tm0v[b * 256 + o] = s * (1.0f / 225.0f);
  }
}

// ---------------------------------------------------------------------------
__global__ __launch_bounds__(512, 4) void chain_kernel(
    const half_t* __restrict__ conv1h, const float* __restrict__ m0v,
    const float* __restrict__ tm0v,
    const half_t* __restrict__ w1h, const half_t* __restrict__ w2h,
    const half_t* __restrict__ w3h,
    const float* __restrict__ w4, const float* __restrict__ w5,
    const float* __restrict__ w6,
    const half_t* __restrict__ inarrh, float* __restrict__ out)
{
  __shared__ __align__(16) char lds[LDSB];
  float*    ldsf   = (float*)lds;
  float*    sm     = (float*)(lds + SMB);
  float*    red    = (float*)(lds + REDB);
  uint16_t* rowoff = (uint16_t*)(lds + ROWB);

  const int tid  = threadIdx.x;
  const int lane = tid & 63;
  const int wvs  = __builtin_amdgcn_readfirstlane(tid >> 6);
  const int bid  = (blockIdx.x & 7) * 290 + (blockIdx.x >> 3);
  const bool is_t = (bid >= B_ * KK_);
  int b, u = 0, v = 0;
  const float* mean_vec;
  if (!is_t) {
    b = bid / KK_;
    int r = bid % KK_;
    u = r / K_; v = r % K_;
    mean_vec = m0v + (size_t)bid * 256;
  } else {
    b = bid - B_ * KK_;
    mean_vec = tm0v + (size_t)b * 256;
  }

  if (tid < SS_) {
    int i = tid / 15, j = tid - i * 15;
    rowoff[tid] = is_t ? (uint16_t)(NROW_C + b * SS_ + tid)
                       : (uint16_t)(b * PP_ + (u + i) * P_ + (v + j));
  }
  ((float*)(lds + W4B))[(tid >> 5) * 36 + (tid & 31)] = w4[tid];
  if (tid < 128) ((float*)(lds + W5B))[(tid >> 4) * 20 + (tid & 15)] = w5[tid];
  if (tid < 8)   ((float*)(lds + W6B))[tid] = w6[tid];

  const half_t* w1base = w1h + (size_t)(16 * wvs + (lane & 15)) * 256 + ((lane >> 4) << 3);
  const int g2 = wvs & 3, h2w = wvs >> 2;
  half8 af2[4];
  {
    const half_t* base = w2h + (size_t)(16 * g2 + (lane & 15)) * 128 + ((lane >> 4) << 3);
#pragma unroll
    for (int kb = 0; kb < 4; ++kb) af2[kb] = *(const half8*)(base + kb * 32);
  }
  const int rt3 = wvs & 1, ct3 = wvs >> 1;
  const half_t* b3ptr = w3h + (size_t)(16 * rt3 + (lane & 15)) * 64 + ((lane >> 4) << 3);
  const int c8  = (lane & 31) * 8;
  const int lhi = lane >> 5;
  half8 mvh;
  {
    f32x4 ma = *(const f32x4*)(mean_vec + c8);
    f32x4 mb = *(const f32x4*)(mean_vec + c8 + 4);
    half4 h0 = pack4(ma), h1 = pack4(mb);
#pragma unroll
    for (int r = 0; r < 4; ++r) { mvh[r] = h0[r]; mvh[4 + r] = h1[r]; }
  }
  __syncthreads();   // rowoff visibility

  auto ldcv = [&](int s) -> half8 {
    return *(const half8*)(conv1h + ((size_t)rowoff[min(s, SS_ - 1)] << 8) + c8);
  };
  auto stage_write = [&](int pos, half8 cv) {
    half8 t = cv + mvh;
    half8 s2 = t * (half_t)0.01f;
    half8 r8 = __builtin_elementwise_max(t, s2);
    const int off = (pos * 512 + c8 * 2) ^ ((pos & 7) << 4);
    *(half8*)(lds + X0B + off) = r8;
  };

  // prologue: stage tile 0 (64 pos)
  {
    const int pbase = 8 * wvs + lhi;
#pragma unroll
    for (int it = 0; it < 4; ++it)
      stage_write(pbase + it * 2, ldcv(pbase + it * 2));
  }
  __syncthreads();

  // tile body, templated on NPOS (this tile's live positions, mult of 16)
  auto process = [&](auto nposc, int ti, int nnext) {
    constexpr int NPOS = decltype(nposc)::value;
    constexpr int NT = NPOS / 16;
    const int s0 = ti * 64;
    const int cnt = min(64, SS_ - s0);

    // ---- layer 1: 256 -> NT*16 pos MFMA, W1 streamed
    f32x4 acc[NT];
#pragma unroll
    for (int nt = 0; nt < NT; ++nt) acc[nt] = (f32x4){0.f, 0.f, 0.f, 0.f};
    {
      const half_t* w1p = w1base;
      asm volatile("" : "+v"(w1p));
#pragma unroll 2
      for (int kb = 0; kb < 8; ++kb) {
        half8 a1 = *(const half8*)(w1p + kb * 32);
        const int kbyte = kb * 64 + ((lane >> 4) << 4);
#pragma unroll
        for (int nt = 0; nt < NT; ++nt) {
          const int pos = nt * 16 + (lane & 15);
          const int off = (pos * 512 + kbyte) ^ ((pos & 7) << 4);
          half8 bfr = *(const half8*)(lds + X0B + off);
          acc[nt] = __builtin_amdgcn_mfma_f32_16x16x32_f16(a1, bfr, acc[nt], 0, 0, 0);
        }
      }
#pragma unroll
      for (int nt = 0; nt < NT; ++nt) {
        const int pos = nt * 16 + (lane & 15);
        f32x4 a;
#pragma unroll
        for (int r = 0; r < 4; ++r) a[r] = fmaxf(acc[nt][r], 0.01f * acc[nt][r]);
        const int ch0 = 16 * wvs + ((lane >> 4) << 2);
        const int off = (pos * 256 + ch0 * 2) ^ ((pos & 7) << 4);
        *(half4*)(lds + X1B + off) = pack4(a);
      }
    }
    __syncthreads();

    // ---- layer 2: 128 -> 64 MFMA; write x2 guarded to pos<NPOS
    f32x4 acc2[2];
#pragma unroll
    for (int nt = 0; nt < 2; ++nt) acc2[nt] = (f32x4){0.f, 0.f, 0.f, 0.f};
#pragma unroll
    for (int kb = 0; kb < 4; ++kb) {
      const int kbyte = kb * 64 + ((lane >> 4) << 4);
#pragma unroll
      for (int nt = 0; nt < 2; ++nt) {
        const int pos = h2w * 32 + nt * 16 + (lane & 15);
        const int off = (pos * 256 + kbyte) ^ ((pos & 7) << 4);
        half8 bfr = *(const half8*)(lds + X1B + off);
        acc2[nt] = __builtin_amdgcn_mfma_f32_16x16x32_f16(af2[kb], bfr, acc2[nt], 0, 0, 0);
      }
    }
#pragma unroll
    for (int nt = 0; nt < 2; ++nt) {
      const int pos = h2w * 32 + nt * 16 + (lane & 15);
      const int ch0 = 16 * g2 + ((lane >> 4) << 2);
      f32x4 a;
#pragma unroll
      for (int r = 0; r < 4; ++r) a[r] = fmaxf(acc2[nt][r], 0.01f * acc2[nt][r]);
      const int off = (pos * 128 + ch0 * 2) ^ ((pos & 7) << 4);
      if constexpr (NPOS < 64) {
        if (pos < NPOS) *(half4*)(lds + X0B + off) = pack4(a);
      } else {
        *(half4*)(lds + X0B + off) = pack4(a);
      }
    }
    __syncthreads();

    // ---- layer 3 phase: cv prefetch (next tile) + L3 MFMA
    half8 cv0, cv1, cv2, cv3;
    const int npw = nnext >> 3;              // 8 or 6 (or 0)
    const int pb = npw * wvs + lhi;
    if (nnext) {
      const int s1 = s0 + 64;
      cv0 = ldcv(s1 + pb);
      cv1 = ldcv(s1 + pb + 2);
      cv2 = ldcv(s1 + pb + 4);
      if (nnext == 64) cv3 = ldcv(s1 + pb + 6);
    }
    {
      f32x4 acc3 = (f32x4){0.f, 0.f, 0.f, 0.f};
      const int pos = ct3 * 16 + (lane & 15);
#pragma unroll
      for (int kb = 0; kb < 2; ++kb) {
        half8 a3 = *(const half8*)(b3ptr + kb * 32);
        const int kbyte = kb * 64 + ((lane >> 4) << 4);
        const int off = (pos * 128 + kbyte) ^ ((pos & 7) << 4);
        half8 bfr = *(const half8*)(lds + X0B + off);
        acc3 = __builtin_amdgcn_mfma_f32_16x16x32_f16(a3, bfr, acc3, 0, 0, 0);
      }
      const int ch0 = 16 * rt3 + ((lane >> 4) << 2);
      f32x4 o4;
#pragma unroll
      for (int r = 0; r < 4; ++r) o4[r] = fmaxf(acc3[r], 0.01f * acc3[r]);
      if constexpr (NPOS < 64) {
        if (pos < NPOS) *(f32x4*)(lds + X3TB + pos * 144 + ch0 * 4) = o4;
      } else {
        *(f32x4*)(lds + X3TB + pos * 144 + ch0 * 4) = o4;
      }
    }
    __syncthreads();

    // ---- tail (layers 4-6) + stage writes for next tile
    {
      const int p = lane >> 3, g = lane & 7;
      const int pos = 8 * wvs + p;
      float a4_0 = 0.f, a4_1 = 0.f;
#pragma unroll
      for (int c0 = 0; c0 < 32; c0 += 4) {
        f32x4 x  = *(const f32x4*)(lds + X3TB + pos * 144 + c0 * 4);
        f32x4 wA = *(const f32x4*)(lds + W4B + (2 * g) * 144 + c0 * 4);
        f32x4 wB = *(const f32x4*)(lds + W4B + (2 * g + 1) * 144 + c0 * 4);
#pragma unroll
        for (int r = 0; r < 4; ++r) {
          a4_0 = fmaf(wA[r], x[r], a4_0);
          a4_1 = fmaf(wB[r], x[r], a4_1);
        }
      }
      f32x2 y4v;
      y4v[0] = fmaxf(a4_0, 0.01f * a4_0);
      y4v[1] = fmaxf(a4_1, 0.01f * a4_1);
      *(f32x2*)(lds + Y4B + pos * 80 + g * 8) = y4v;
      float a5 = 0.f;
#pragma unroll
      for (int c0 = 0; c0 < 16; c0 += 4) {
        f32x4 x = *(const f32x4*)(lds + Y4B + pos * 80 + c0 * 4);
        f32x4 w = *(const f32x4*)(lds + W5B + g * 80 + c0 * 4);
#pragma unroll
        for (int r = 0; r < 4; ++r) a5 = fmaf(w[r], x[r], a5);
      }
      a5 = fmaxf(a5, 0.01f * a5);
      float t6 = ((float*)(lds + W6B))[g] * a5;
      t6 += __shfl_xor(t6, 1);
      t6 += __shfl_xor(t6, 2);
      t6 += __shfl_xor(t6, 4);
      if (g == 0 && pos < cnt) sm[s0 + pos] = t6;

      if (nnext) {
        stage_write(pb,     cv0);
        stage_write(pb + 2, cv1);
        stage_write(pb + 4, cv2);
        if (nnext == 64) stage_write(pb + 6, cv3);
      }
    }
    __syncthreads();
  };

  process(IC<64>{}, 0, 64);
  process(IC<64>{}, 1, 64);
  process(IC<64>{}, 2, 48);
  process(IC<48>{}, 3, 0);

  // ---- softmax over 225 logits
  float vv = (tid < SS_) ? sm[tid] : -1e30f;
  float m = vv;
#pragma unroll
  for (int off = 32; off >= 1; off >>= 1) m = fmaxf(m, __shfl_xor(m, off));
  if (lane == 0) red[wvs] = m;
  __syncthreads();
  m = red[0];
#pragma unroll
  for (int w = 1; w < 8; ++w) m = fmaxf(m, red[w]);
  float e = (tid < SS_) ? __expf(vv - m) : 0.f;
  float ss = e;
#pragma unroll
  for (int off = 32; off >= 1; off >>= 1) ss += __shfl_xor(ss, off);
  __syncthreads();
  if (lane == 0) red[wvs] = ss;
  __syncthreads();
  float Stot = red[0];
#pragma unroll
  for (int w = 1; w < 8; ++w) Stot += red[w];
  if (tid < SS_) sm[tid] = e / Stot;
  __syncthreads();

  // ---- weighted channel sum: 2 channels/thread (f16 features), 4-way pos split
  {
    const int c2 = (tid & 127) * 2;
    const int q  = tid >> 7;
    float accx = 0.f, accy = 0.f;
    for (int s = q; s < SS_; s += 4) {
      h2 ft = *(const h2*)(inarrh + ((size_t)rowoff[s] << 8) + c2);
      float w = sm[s];
      accx = fmaf(w, (float)ft[0], accx);
      accy = fmaf(w, (float)ft[1], accy);
    }
    __syncthreads();
    ldsf[q * 256 + c2]     = accx;
    ldsf[q * 256 + c2 + 1] = accy;
    __syncthreads();
    if (tid < 256) {
      float tot = ldsf[tid] + ldsf[256 + tid] + ldsf[512 + tid] + ldsf[768 + tid];
      if (!is_t) out[2048 + ((size_t)(b * 256 + tid) * 17 + u) * 17 + v] = tot;
      else       out[b * 256 + tid] = tot;
    }
  }
}

// ---------------------------------------------------------------------------
extern "C" void kernel_launch(void* const* d_in, const int* in_sizes, int n_in,
                              void* d_out, int out_size, void* d_ws, size_t ws_size,
                              hipStream_t stream)
{
  const float* templ = (const float*)d_in[0];
  const float* cand  = (const float*)d_in[1];
  const float* w0 = (const float*)d_in[2];
  const float* w1 = (const float*)d_in[3];
  const float* w2 = (const float*)d_in[4];
  const float* w3 = (const float*)d_in[5];
  const float* w4 = (const float*)d_in[6];
  const float* w5 = (const float*)d_in[7];
  const float* w6 = (const float*)d_in[8];

  float* ws    = (float*)d_ws;
  float* gout  = ws + OFF_GOUT;
  float* rows  = ws + OFF_ROWS;
  float* m0v   = ws + OFF_M0;
  float* tm0v  = ws + OFF_TM0;
  half_t* inarrh = (half_t*)(ws + OFF_F16);
  half_t* conv1h = inarrh + (size_t)NROW * 256;
  half_t* w0h  = conv1h + (size_t)NROW * 256;
  half_t* w1h  = w0h + NW0H;
  half_t* w2h  = w1h + 128 * 256;
  half_t* w3h  = w2h + 64 * 128;
  float* outf  = (float*)d_out;

  prep_kernel<<<NFEATB + 88, 256, 0, stream>>>(templ, cand, w0, w1, w2, w3,
                                               inarrh, w0h, w1h, w2h, w3h);
  l0gemm_kernel<<<NROW / 16, 512, 0, stream>>>(inarrh, w0h, conv1h, gout);
  rowsum_kernel<<<B_ * 31 * 17, 256, 0, stream>>>(gout, rows);
  colsum_tmean_kernel<<<B_ * KK_ + B_, 256, 0, stream>>>(rows, gout, m0v, tm0v);
  chain_kernel<<<B_ * KK_ + B_, 512, 0, stream>>>(conv1h, m0v, tm0v,
                                                  w1h, w2h, w3h, w4, w5, w6,
                                                  inarrh, outf);
}